// Round 9
// baseline (515.893 us; speedup 1.0000x reference)
//
#include <hip/hip_runtime.h>
#include <math.h>

// ---------------------------------------------------------------------------
// GCN-VAE forward, round 9.
//  - k_fill: one int4 pack {w,tok,src,_} per edge (single 16B store: 1 line
//    drag not 2), 4 edges/thread for MLP. (R8: 60us, VALU 0.7%, 92MB write)
//  - single-block scan kernel replaces 3-kernel scan; one memset (degint and
//    cursor adjacent). 12 dispatches.
// ---------------------------------------------------------------------------

typedef __attribute__((ext_vector_type(8))) short bf16x8;
typedef __attribute__((ext_vector_type(4))) float f32x4;

__device__ inline unsigned short f2bf(float x) {
    unsigned u = __float_as_uint(x);
    return (unsigned short)((u + 0x7FFFu + ((u >> 16) & 1u)) >> 16);
}
__device__ inline float bf2f(unsigned short h) {
    return __uint_as_float(((unsigned)h) << 16);
}

// ============================ CSR build ====================================
__global__ __launch_bounds__(256) void k_deg_count(const int* __restrict__ dst,
                                                   int* __restrict__ degint, int E) {
    int e = blockIdx.x * 256 + threadIdx.x;
    if (e < E) atomicAdd(&degint[dst[e]], 1);
}

// single-block scan of (degint[i]+1) -> exclusive row_ptr; also dinv
__global__ __launch_bounds__(1024) void k_scan_one(
        const int* __restrict__ degint, int* __restrict__ row_ptr,
        float* __restrict__ dinv, int N, int T) {
    __shared__ int s[1024];
    const int t = threadIdx.x;
    const int CH = (N + 1023) >> 10;
    const int lo = t * CH;
    const int hi = (lo + CH < N) ? lo + CH : N;
    int sum = 0;
    for (int i = lo; i < hi; ++i) sum += degint[i] + 1;
    s[t] = sum;
    __syncthreads();
    for (int off = 1; off < 1024; off <<= 1) {
        int v = (t >= off) ? s[t - off] : 0;
        __syncthreads();
        s[t] += v;
        __syncthreads();
    }
    int base = s[t] - sum;                       // exclusive prefix
    for (int i = lo; i < hi; ++i) {
        int d = degint[i] + 1;
        row_ptr[i] = base;
        dinv[i] = rsqrtf((float)d);
        base += d;
    }
    if (t == 0) row_ptr[N] = T;
}

// fill packs: pack = {w, x[src], src, 0}; 4 edges per thread for MLP
__global__ __launch_bounds__(256) void k_fill(
        const int* __restrict__ src, const int* __restrict__ dst,
        const int* __restrict__ x, const float* __restrict__ dinv,
        const int* __restrict__ row_ptr, int* __restrict__ cursor,
        int4* __restrict__ pack, int E, int N) {
    const int base = (blockIdx.x * 256 + threadIdx.x) * 4;
#pragma unroll
    for (int j = 0; j < 4; ++j) {
        int e = base + j;
        if (e < E) {
            int s = src[e], d = dst[e];
            float w = dinv[s] * dinv[d];
            int pos = row_ptr[d] + atomicAdd(&cursor[d], 1);
            pack[pos] = make_int4(__float_as_int(w), x[s], s, 0);
        } else if (e < E + N) {
            int i = e - E;
            float di = dinv[i];
            int pos = row_ptr[i] + atomicAdd(&cursor[i], 1);
            pack[pos] = make_int4(__float_as_int(di * di), x[i], i, 0);
        }
    }
}

// ===== merged weight transpose: 5 jobs, B[K,N] -> Bt[N,K] bf16 =============
__global__ __launch_bounds__(256) void k_cvt_all(
        const float* __restrict__ B0, unsigned short* __restrict__ h0, int K0, int N0,
        const float* __restrict__ B1, unsigned short* __restrict__ h1, int K1, int N1,
        const float* __restrict__ B2, unsigned short* __restrict__ h2, int K2, int N2,
        const float* __restrict__ B3, unsigned short* __restrict__ h3, int K3, int N3,
        const float* __restrict__ B4, unsigned short* __restrict__ h4, int K4, int N4) {
    const float* B; unsigned short* Bh; int K, Ncol;
    switch (blockIdx.y) {
        case 0: B = B0; Bh = h0; K = K0; Ncol = N0; break;
        case 1: B = B1; Bh = h1; K = K1; Ncol = N1; break;
        case 2: B = B2; Bh = h2; K = K2; Ncol = N2; break;
        case 3: B = B3; Bh = h3; K = K3; Ncol = N3; break;
        default: B = B4; Bh = h4; K = K4; Ncol = N4; break;
    }
    int i = blockIdx.x * 256 + threadIdx.x;
    if (i >= K * Ncol) return;
    int k = i / Ncol, n = i - k * Ncol;
    Bh[(long)n * K + k] = f2bf(B[i]);
}

// ============ small fp32 GEMM with bf16 output (embW1 table) ===============
__global__ __launch_bounds__(256) void k_gemm_f32(
        const float* __restrict__ A, const float* __restrict__ B,
        unsigned short* __restrict__ Cb, int M, int K, int Ncol) {
    constexpr int BM = 64, BN = 64, BK = 16;
    __shared__ float As[BK][BM];
    __shared__ float Bs[BK][BN];
    const int tid = threadIdx.x;
    const int tx = tid & 15, ty = tid >> 4;
    const int rowBase = blockIdx.x * BM;
    const int colBase = blockIdx.y * BN;
    const int lr = tid >> 2, lc4 = tid & 3;
    const int br = tid >> 4, bc4 = tid & 15;
    const int arow = rowBase + lr;
    const int K4 = K >> 2, N4 = Ncol >> 2;
    const float4* A4 = (const float4*)A;
    const float4* B4 = (const float4*)B;
    float acc[4][4] = {{0.f}};
    for (int k0 = 0; k0 < K; k0 += BK) {
        float4 av = make_float4(0.f, 0.f, 0.f, 0.f);
        if (arow < M) av = A4[(long)arow * K4 + (k0 >> 2) + lc4];
        As[lc4 * 4 + 0][lr] = av.x;
        As[lc4 * 4 + 1][lr] = av.y;
        As[lc4 * 4 + 2][lr] = av.z;
        As[lc4 * 4 + 3][lr] = av.w;
        float4 bv = B4[(long)(k0 + br) * N4 + (colBase >> 2) + bc4];
        *(float4*)&Bs[br][bc4 * 4] = bv;
        __syncthreads();
#pragma unroll
        for (int k = 0; k < BK; ++k) {
            float4 a4v = *(const float4*)&As[k][ty * 4];
            float4 b4v = *(const float4*)&Bs[k][tx * 4];
            float aa[4] = {a4v.x, a4v.y, a4v.z, a4v.w};
            float bb[4] = {b4v.x, b4v.y, b4v.z, b4v.w};
#pragma unroll
            for (int i = 0; i < 4; ++i)
#pragma unroll
                for (int j = 0; j < 4; ++j)
                    acc[i][j] = fmaf(aa[i], bb[j], acc[i][j]);
        }
        __syncthreads();
    }
#pragma unroll
    for (int i = 0; i < 4; ++i) {
        int row = rowBase + ty * 4 + i;
        if (row < M) {
            ushort4 o;
            o.x = f2bf(acc[i][0]); o.y = f2bf(acc[i][1]);
            o.z = f2bf(acc[i][2]); o.w = f2bf(acc[i][3]);
            *(ushort4*)&Cb[(long)row * Ncol + colBase + tx * 4] = o;
        }
    }
}

// ====== MFMA GEMM: C = A(bf16) @ Bt(bf16), BM=128 BN=64 BK=32 ==============
template<bool RELU, bool BIAS, bool OUTBF>
__global__ __launch_bounds__(256) void k_gemm_mfma(
        const unsigned short* __restrict__ A, const unsigned short* __restrict__ Bt,
        const float* __restrict__ bias, float* __restrict__ Cf,
        unsigned short* __restrict__ Cb, int M, int K, int Ncol) {
    __shared__ unsigned short Ash[128][40];
    __shared__ unsigned short Bsh[64][40];
    const int tid = threadIdx.x;
    const int lane = tid & 63, w = tid >> 6;
    const int fr = lane & 15, quad = lane >> 4;
    const int wm0 = w * 32;
    const int rowBase = blockIdx.x * 128;
    const int colBase = blockIdx.y * 64;

    const int arow = tid >> 1;
    const int ahalf = (tid & 1) << 4;
    int agrow = rowBase + arow; if (agrow >= M) agrow = M - 1;
    const long abase = (long)agrow * K + ahalf;
    const int brow = tid >> 2;
    const int bseg = (tid & 3) << 3;
    const long bbase = (long)(colBase + brow) * K + bseg;

    f32x4 acc[2][4];
#pragma unroll
    for (int i = 0; i < 2; ++i)
#pragma unroll
        for (int j = 0; j < 4; ++j) acc[i][j] = (f32x4){0.f, 0.f, 0.f, 0.f};

    for (int k0 = 0; k0 < K; k0 += 32) {
        *(bf16x8*)&Ash[arow][ahalf]     = *(const bf16x8*)&A[abase + k0];
        *(bf16x8*)&Ash[arow][ahalf + 8] = *(const bf16x8*)&A[abase + k0 + 8];
        *(bf16x8*)&Bsh[brow][bseg]      = *(const bf16x8*)&Bt[bbase + k0];
        __syncthreads();
        bf16x8 ahf[2], bhf[4];
#pragma unroll
        for (int i = 0; i < 2; ++i)
            ahf[i] = *(const bf16x8*)&Ash[wm0 + i * 16 + fr][quad * 8];
#pragma unroll
        for (int j = 0; j < 4; ++j)
            bhf[j] = *(const bf16x8*)&Bsh[j * 16 + fr][quad * 8];
#pragma unroll
        for (int i = 0; i < 2; ++i)
#pragma unroll
            for (int j = 0; j < 4; ++j)
                acc[i][j] = __builtin_amdgcn_mfma_f32_16x16x32_bf16(
                    ahf[i], bhf[j], acc[i][j], 0, 0, 0);
        __syncthreads();
    }

#pragma unroll
    for (int i = 0; i < 2; ++i) {
        const int rowb = rowBase + wm0 + i * 16 + quad * 4;
#pragma unroll
        for (int j = 0; j < 4; ++j) {
            const int col = colBase + j * 16 + fr;
            const float bv = BIAS ? bias[col] : 0.f;
#pragma unroll
            for (int r = 0; r < 4; ++r) {
                const int row = rowb + r;
                if (row < M) {
                    float v = acc[i][j][r] + bv;
                    if (RELU) v = fmaxf(v, 0.f);
                    const long o = (long)row * Ncol + col;
                    if (OUTBF) Cb[o] = f2bf(v);
                    else       Cf[o] = v;
                }
            }
        }
    }
}

// == fused heads: [mu|lv] = h2 @ Wml; z; cap — BM=64 BN=128 K=256 ===========
__global__ __launch_bounds__(256) void k_gemm_heads(
        const unsigned short* __restrict__ A, const unsigned short* __restrict__ Bt,
        const float* __restrict__ bmu, const float* __restrict__ blv,
        const float* __restrict__ eps, const float* __restrict__ Wcap,
        const float* __restrict__ bcap, float* __restrict__ mu,
        float* __restrict__ lv, unsigned short* __restrict__ Zh,
        float* __restrict__ cap, int M) {
    constexpr int K = 256;
    __shared__ unsigned short Ash[64][40];
    __shared__ unsigned short Bsh[128][40];
    const int tid = threadIdx.x;
    const int lane = tid & 63, w = tid >> 6;
    const int fr = lane & 15, quad = lane >> 4;
    const int wm0 = w * 16;
    const int rowBase = blockIdx.x * 64;

    const int arow = tid >> 2;
    const int aseg = (tid & 3) << 3;
    int agrow = rowBase + arow; if (agrow >= M) agrow = M - 1;
    const long abase = (long)agrow * K + aseg;
    const int brow = tid >> 1;
    const int bseg = (tid & 1) << 4;
    const long bbase = (long)brow * K + bseg;

    f32x4 acc[8];
#pragma unroll
    for (int j = 0; j < 8; ++j) acc[j] = (f32x4){0.f, 0.f, 0.f, 0.f};

    for (int k0 = 0; k0 < K; k0 += 32) {
        *(bf16x8*)&Ash[arow][aseg] = *(const bf16x8*)&A[abase + k0];
        *(bf16x8*)&Bsh[brow][bseg]     = *(const bf16x8*)&Bt[bbase + k0];
        *(bf16x8*)&Bsh[brow][bseg + 8] = *(const bf16x8*)&Bt[bbase + k0 + 8];
        __syncthreads();
        bf16x8 ahf = *(const bf16x8*)&Ash[wm0 + fr][quad * 8];
#pragma unroll
        for (int j = 0; j < 8; ++j) {
            bf16x8 bhf = *(const bf16x8*)&Bsh[j * 16 + fr][quad * 8];
            acc[j] = __builtin_amdgcn_mfma_f32_16x16x32_bf16(ahf, bhf, acc[j], 0, 0, 0);
        }
        __syncthreads();
    }

    float capacc[4] = {0.f, 0.f, 0.f, 0.f};
#pragma unroll
    for (int j = 0; j < 4; ++j) {
        const int c = j * 16 + fr;
        const float bm = bmu[c], bl = blv[c];
        const float wc = Wcap[c];
#pragma unroll
        for (int r = 0; r < 4; ++r) {
            const int row = rowBase + wm0 + quad * 4 + r;
            if (row < M) {
                const long o = (long)row * 64 + c;
                float mv = acc[j][r] + bm;
                float lvv = acc[j + 4][r] + bl;
                mu[o] = mv;
                lv[o] = lvv;
                float zz = fmaf(eps[o], expf(0.5f * lvv), mv);
                Zh[o] = f2bf(zz);
                capacc[r] = fmaf(zz, wc, capacc[r]);
            }
        }
    }
    const float b0 = bcap[0];
#pragma unroll
    for (int r = 0; r < 4; ++r) {
        float v = capacc[r];
        v += __shfl_xor(v, 1, 64);
        v += __shfl_xor(v, 2, 64);
        v += __shfl_xor(v, 4, 64);
        v += __shfl_xor(v, 8, 64);
        if (fr == 0) {
            const int row = rowBase + wm0 + quad * 4 + r;
            if (row < M) cap[row] = 1.f / (1.f + expf(-(v + b0)));
        }
    }
}

// ==== conv1 agg: h1 = relu(b1 + sum_e w_e * T[tok_e]) ======================
__global__ __launch_bounds__(256) void k_agg_tab(
        const unsigned short* __restrict__ tab, const int* __restrict__ row_ptr,
        const int4* __restrict__ pack, const float* __restrict__ bias,
        unsigned short* __restrict__ h1, int N) {
    const int wave = threadIdx.x >> 6;
    const int lane = threadIdx.x & 63;
    const int node = blockIdx.x * 4 + wave;
    if (node >= N) return;
    const ushort4* t4 = (const ushort4*)tab;
    float ax = 0.f, ay = 0.f, az = 0.f, aw = 0.f;
    const int beg = row_ptr[node], end = row_ptr[node + 1];
    int e = beg;
    for (; e + 4 <= end; e += 4) {
        int4 p0 = pack[e], p1 = pack[e + 1], p2 = pack[e + 2], p3 = pack[e + 3];
        ushort4 v0 = t4[(long)p0.y * 64 + lane];
        ushort4 v1 = t4[(long)p1.y * 64 + lane];
        ushort4 v2 = t4[(long)p2.y * 64 + lane];
        ushort4 v3 = t4[(long)p3.y * 64 + lane];
        float w0 = __int_as_float(p0.x), w1 = __int_as_float(p1.x);
        float w2 = __int_as_float(p2.x), w3 = __int_as_float(p3.x);
        ax = fmaf(bf2f(v0.x), w0, ax); ay = fmaf(bf2f(v0.y), w0, ay);
        az = fmaf(bf2f(v0.z), w0, az); aw = fmaf(bf2f(v0.w), w0, aw);
        ax = fmaf(bf2f(v1.x), w1, ax); ay = fmaf(bf2f(v1.y), w1, ay);
        az = fmaf(bf2f(v1.z), w1, az); aw = fmaf(bf2f(v1.w), w1, aw);
        ax = fmaf(bf2f(v2.x), w2, ax); ay = fmaf(bf2f(v2.y), w2, ay);
        az = fmaf(bf2f(v2.z), w2, az); aw = fmaf(bf2f(v2.w), w2, aw);
        ax = fmaf(bf2f(v3.x), w3, ax); ay = fmaf(bf2f(v3.y), w3, ay);
        az = fmaf(bf2f(v3.z), w3, az); aw = fmaf(bf2f(v3.w), w3, aw);
    }
    for (; e < end; ++e) {
        int4 p = pack[e];
        float w0 = __int_as_float(p.x);
        ushort4 v = t4[(long)p.y * 64 + lane];
        ax = fmaf(bf2f(v.x), w0, ax); ay = fmaf(bf2f(v.y), w0, ay);
        az = fmaf(bf2f(v.z), w0, az); aw = fmaf(bf2f(v.w), w0, aw);
    }
    float4 b = ((const float4*)bias)[lane];
    ax = fmaxf(ax + b.x, 0.f); ay = fmaxf(ay + b.y, 0.f);
    az = fmaxf(az + b.z, 0.f); aw = fmaxf(aw + b.w, 0.f);
    ushort4 o;
    o.x = f2bf(ax); o.y = f2bf(ay); o.z = f2bf(az); o.w = f2bf(aw);
    ((ushort4*)h1)[(long)node * 64 + lane] = o;
}

// ==== conv2 agg: a2 = sum_e w_e * h1[src_e] ================================
__global__ __launch_bounds__(256) void k_agg_nb(
        const unsigned short* __restrict__ h1, const int* __restrict__ row_ptr,
        const int4* __restrict__ pack, unsigned short* __restrict__ Ob, int N) {
    const int wave = threadIdx.x >> 6;
    const int lane = threadIdx.x & 63;
    const int node = blockIdx.x * 4 + wave;
    if (node >= N) return;
    const ushort4* h4 = (const ushort4*)h1;
    float ax = 0.f, ay = 0.f, az = 0.f, aw = 0.f;
    const int beg = row_ptr[node], end = row_ptr[node + 1];
    int e = beg;
    for (; e + 4 <= end; e += 4) {
        int4 p0 = pack[e], p1 = pack[e + 1], p2 = pack[e + 2], p3 = pack[e + 3];
        ushort4 v0 = h4[(long)p0.z * 64 + lane];
        ushort4 v1 = h4[(long)p1.z * 64 + lane];
        ushort4 v2 = h4[(long)p2.z * 64 + lane];
        ushort4 v3 = h4[(long)p3.z * 64 + lane];
        float w0 = __int_as_float(p0.x), w1 = __int_as_float(p1.x);
        float w2 = __int_as_float(p2.x), w3 = __int_as_float(p3.x);
        ax = fmaf(bf2f(v0.x), w0, ax); ay = fmaf(bf2f(v0.y), w0, ay);
        az = fmaf(bf2f(v0.z), w0, az); aw = fmaf(bf2f(v0.w), w0, aw);
        ax = fmaf(bf2f(v1.x), w1, ax); ay = fmaf(bf2f(v1.y), w1, ay);
        az = fmaf(bf2f(v1.z), w1, az); aw = fmaf(bf2f(v1.w), w1, aw);
        ax = fmaf(bf2f(v2.x), w2, ax); ay = fmaf(bf2f(v2.y), w2, ay);
        az = fmaf(bf2f(v2.z), w2, az); aw = fmaf(bf2f(v2.w), w2, aw);
        ax = fmaf(bf2f(v3.x), w3, ax); ay = fmaf(bf2f(v3.y), w3, ay);
        az = fmaf(bf2f(v3.z), w3, aw == aw ? az : az), aw = fmaf(bf2f(v3.w), w3, aw);
    }
    for (; e < end; ++e) {
        int4 p = pack[e];
        float w0 = __int_as_float(p.x);
        ushort4 v = h4[(long)p.z * 64 + lane];
        ax = fmaf(bf2f(v.x), w0, ax); ay = fmaf(bf2f(v.y), w0, ay);
        az = fmaf(bf2f(v.z), w0, az); aw = fmaf(bf2f(v.w), w0, aw);
    }
    ushort4 o;
    o.x = f2bf(ax); o.y = f2bf(ay); o.z = f2bf(az); o.w = f2bf(aw);
    ((ushort4*)Ob)[(long)node * 64 + lane] = o;
}

extern "C" void kernel_launch(void* const* d_in, const int* in_sizes, int n_in,
                              void* d_out, int out_size, void* d_ws, size_t ws_size,
                              hipStream_t stream) {
    const int*   x    = (const int*)d_in[0];
    const int*   ei   = (const int*)d_in[1];
    const float* eps  = (const float*)d_in[2];
    const float* emb  = (const float*)d_in[3];
    const float* W1   = (const float*)d_in[4];
    const float* b1   = (const float*)d_in[5];
    const float* W2   = (const float*)d_in[6];
    const float* b2   = (const float*)d_in[7];
    const float* Wmu  = (const float*)d_in[8];
    const float* bmu  = (const float*)d_in[9];
    const float* Wlv  = (const float*)d_in[10];
    const float* blv  = (const float*)d_in[11];
    const float* W3   = (const float*)d_in[12];
    const float* b3   = (const float*)d_in[13];
    const float* W4   = (const float*)d_in[14];
    const float* b4   = (const float*)d_in[15];
    const float* Wcap = (const float*)d_in[16];
    const float* bcap = (const float*)d_in[17];

    const int N = in_sizes[0];
    const int E = in_sizes[1] / 2;
    const int H = in_sizes[5];            // 256
    const int L = in_sizes[9];            // 64
    const int V = in_sizes[15];           // 128
    const int F = in_sizes[4] / H;        // 128
    const int T = E + N;

    const int* src = ei;
    const int* dst = ei + E;

    // ---- workspace carve-up (degint+cursor adjacent: single memset) ----
    char* w = (char*)d_ws;
    unsigned short* h1b  = (unsigned short*)w; w += (size_t)N * H * 2;
    unsigned short* a2b  = (unsigned short*)w; w += (size_t)N * H * 2;
    unsigned short* h2b  = (unsigned short*)w; w += (size_t)N * H * 2;
    unsigned short* zh   = (unsigned short*)w; w += (size_t)N * L * 2;
    int*   degint = (int*)w;   w += (size_t)N * 4;
    int*   cursor = (int*)w;   w += (size_t)N * 4;
    int*   rowp   = (int*)w;   w += (size_t)(N + 1) * 4;
    float* dinv   = (float*)w; w += (size_t)N * 4;
    int4*  pack   = (int4*)w;  w += (size_t)T * 16;
    unsigned short* tabH = (unsigned short*)w; w += (size_t)V * H * 2;
    unsigned short* W2t  = (unsigned short*)w; w += (size_t)H * H * 2;
    unsigned short* Wml  = (unsigned short*)w; w += (size_t)H * 2 * L * 2;
    unsigned short* W3t  = (unsigned short*)w; w += (size_t)L * H * 2;
    unsigned short* W4t  = (unsigned short*)w; w += (size_t)H * V * 2;

    unsigned short* tb = a2b;   // a2 dead after GEMM2; reuse for t

    float* outp    = (float*)d_out;
    float* recon   = outp;                               // [N, V]
    float* cap     = outp + (size_t)N * V;               // [N, 1]
    float* mu      = outp + (size_t)N * V + N;           // [N, L]
    float* logvar  = mu + (size_t)N * L;                 // [N, L]

    const int nE  = (E + 255) / 256;
    const int nT4 = (T + 1023) / 1024;
    const int gM128 = (N + 127) / 128;
    const int gM64  = (N + 63) / 64;

    // ---- degree / dinv / CSR pack ----
    hipMemsetAsync(degint, 0, (size_t)N * 8, stream);    // degint + cursor
    k_deg_count<<<nE, 256, 0, stream>>>(dst, degint, E);
    k_scan_one<<<1, 1024, 0, stream>>>(degint, rowp, dinv, N, T);
    k_fill<<<nT4, 256, 0, stream>>>(src, dst, x, dinv, rowp, cursor, pack, E, N);

    // ---- weight conversions: one launch, 5 jobs ----
    k_cvt_all<<<dim3((H * H + 255) / 256, 5), 256, 0, stream>>>(
        W2, W2t, H, H,
        Wmu, Wml, H, L,
        Wlv, Wml + (size_t)L * H, H, L,
        W3, W3t, L, H,
        W4, W4t, H, V);

    // ---- conv1: embW1 = emb @ W1 -> bf16 table; agg -> h1 bf16 ----
    k_gemm_f32<<<dim3(V / 64, H / 64), 256, 0, stream>>>(emb, W1, tabH, V, F, H);
    k_agg_tab<<<(N + 3) / 4, 256, 0, stream>>>(tabH, rowp, pack, b1, h1b, N);

    // ---- conv2: a2 = A_hat h1; h2 = relu(a2 @ W2 + b2) -> bf16 ----
    k_agg_nb<<<(N + 3) / 4, 256, 0, stream>>>(h1b, rowp, pack, a2b, N);
    k_gemm_mfma<true, true, true><<<dim3(gM128, H / 64), 256, 0, stream>>>(
        a2b, W2t, b2, nullptr, h2b, N, H, H);

    // ---- fused heads: mu, logvar, z, cap ----
    k_gemm_heads<<<gM64, 256, 0, stream>>>(
        h2b, Wml, bmu, blv, eps, Wcap, bcap, mu, logvar, zh, cap, N);

    // ---- decode: t = relu(z@W3+b3) bf16; recon = t@W4+b4 fp32 ----
    k_gemm_mfma<true, true, true><<<dim3(gM128, H / 64), 256, 0, stream>>>(
        zh, W3t, b3, nullptr, tb, N, L, H);
    k_gemm_mfma<false, true, false><<<dim3(gM128, V / 64), 256, 0, stream>>>(
        tb, W4t, b4, recon, nullptr, N, H, V);
}

// Round 10
// 422.457 us; speedup vs baseline: 1.2212x; 1.2212x over previous
//
#include <hip/hip_runtime.h>
#include <math.h>

// ---------------------------------------------------------------------------
// GCN-VAE forward, round 10 = R9 with the single-block scan reverted.
// R9 post-mortem: k_scan_one (1 block) ran at 0.14% occupancy = 109us.
// Multi-block 3-kernel scan restored (was <10us in R8); int4-pack k_fill
// kept (R9 validated: dropped out of top-5 from 60us).
// ---------------------------------------------------------------------------

typedef __attribute__((ext_vector_type(8))) short bf16x8;
typedef __attribute__((ext_vector_type(4))) float f32x4;

__device__ inline unsigned short f2bf(float x) {
    unsigned u = __float_as_uint(x);
    return (unsigned short)((u + 0x7FFFu + ((u >> 16) & 1u)) >> 16);
}
__device__ inline float bf2f(unsigned short h) {
    return __uint_as_float(((unsigned)h) << 16);
}

// ============================ CSR build ====================================
__global__ __launch_bounds__(256) void k_deg_count(const int* __restrict__ dst,
                                                   int* __restrict__ degint, int E) {
    int e = blockIdx.x * 256 + threadIdx.x;
    if (e < E) atomicAdd(&degint[dst[e]], 1);
}

// multi-block scan over (degint+1); emits dinv = rsqrt(deg)
#define SCAN_BLOCK 1024
__global__ __launch_bounds__(SCAN_BLOCK) void k_scan_local(
        const int* __restrict__ degint, int* __restrict__ row_ptr,
        int* __restrict__ bsum, float* __restrict__ dinv, int N) {
    __shared__ int s[SCAN_BLOCK];
    int gid = blockIdx.x * SCAN_BLOCK + threadIdx.x;
    int d = (gid < N) ? (degint[gid] + 1) : 0;     // +1 self-loop
    if (gid < N) dinv[gid] = rsqrtf((float)d);
    s[threadIdx.x] = d;
    __syncthreads();
    for (int off = 1; off < SCAN_BLOCK; off <<= 1) {
        int t = (threadIdx.x >= off) ? s[threadIdx.x - off] : 0;
        __syncthreads();
        s[threadIdx.x] += t;
        __syncthreads();
    }
    if (gid < N) row_ptr[gid] = s[threadIdx.x] - d;          // exclusive
    if (threadIdx.x == SCAN_BLOCK - 1) bsum[blockIdx.x] = s[SCAN_BLOCK - 1];
}

__global__ void k_scan_bsum(int* __restrict__ bsum, int nb) {
    if (blockIdx.x == 0 && threadIdx.x == 0) {
        int acc = 0;
        for (int i = 0; i < nb; ++i) { int v = bsum[i]; bsum[i] = acc; acc += v; }
    }
}

__global__ __launch_bounds__(256) void k_scan_add(int* __restrict__ row_ptr,
                                                  const int* __restrict__ bsum,
                                                  int N, int T) {
    int gid = blockIdx.x * 256 + threadIdx.x;
    if (gid < N) row_ptr[gid] += bsum[gid / SCAN_BLOCK];
    if (gid == 0) row_ptr[N] = T;                 // T = E + N
}

// fill packs: pack = {w, x[src], src, 0}; 4 edges per thread for MLP
__global__ __launch_bounds__(256) void k_fill(
        const int* __restrict__ src, const int* __restrict__ dst,
        const int* __restrict__ x, const float* __restrict__ dinv,
        const int* __restrict__ row_ptr, int* __restrict__ cursor,
        int4* __restrict__ pack, int E, int N) {
    const int base = (blockIdx.x * 256 + threadIdx.x) * 4;
#pragma unroll
    for (int j = 0; j < 4; ++j) {
        int e = base + j;
        if (e < E) {
            int s = src[e], d = dst[e];
            float w = dinv[s] * dinv[d];
            int pos = row_ptr[d] + atomicAdd(&cursor[d], 1);
            pack[pos] = make_int4(__float_as_int(w), x[s], s, 0);
        } else if (e < E + N) {
            int i = e - E;
            float di = dinv[i];
            int pos = row_ptr[i] + atomicAdd(&cursor[i], 1);
            pack[pos] = make_int4(__float_as_int(di * di), x[i], i, 0);
        }
    }
}

// ===== merged weight transpose: 5 jobs, B[K,N] -> Bt[N,K] bf16 =============
__global__ __launch_bounds__(256) void k_cvt_all(
        const float* __restrict__ B0, unsigned short* __restrict__ h0, int K0, int N0,
        const float* __restrict__ B1, unsigned short* __restrict__ h1, int K1, int N1,
        const float* __restrict__ B2, unsigned short* __restrict__ h2, int K2, int N2,
        const float* __restrict__ B3, unsigned short* __restrict__ h3, int K3, int N3,
        const float* __restrict__ B4, unsigned short* __restrict__ h4, int K4, int N4) {
    const float* B; unsigned short* Bh; int K, Ncol;
    switch (blockIdx.y) {
        case 0: B = B0; Bh = h0; K = K0; Ncol = N0; break;
        case 1: B = B1; Bh = h1; K = K1; Ncol = N1; break;
        case 2: B = B2; Bh = h2; K = K2; Ncol = N2; break;
        case 3: B = B3; Bh = h3; K = K3; Ncol = N3; break;
        default: B = B4; Bh = h4; K = K4; Ncol = N4; break;
    }
    int i = blockIdx.x * 256 + threadIdx.x;
    if (i >= K * Ncol) return;
    int k = i / Ncol, n = i - k * Ncol;
    Bh[(long)n * K + k] = f2bf(B[i]);
}

// ============ small fp32 GEMM with bf16 output (embW1 table) ===============
__global__ __launch_bounds__(256) void k_gemm_f32(
        const float* __restrict__ A, const float* __restrict__ B,
        unsigned short* __restrict__ Cb, int M, int K, int Ncol) {
    constexpr int BM = 64, BN = 64, BK = 16;
    __shared__ float As[BK][BM];
    __shared__ float Bs[BK][BN];
    const int tid = threadIdx.x;
    const int tx = tid & 15, ty = tid >> 4;
    const int rowBase = blockIdx.x * BM;
    const int colBase = blockIdx.y * BN;
    const int lr = tid >> 2, lc4 = tid & 3;
    const int br = tid >> 4, bc4 = tid & 15;
    const int arow = rowBase + lr;
    const int K4 = K >> 2, N4 = Ncol >> 2;
    const float4* A4 = (const float4*)A;
    const float4* B4 = (const float4*)B;
    float acc[4][4] = {{0.f}};
    for (int k0 = 0; k0 < K; k0 += BK) {
        float4 av = make_float4(0.f, 0.f, 0.f, 0.f);
        if (arow < M) av = A4[(long)arow * K4 + (k0 >> 2) + lc4];
        As[lc4 * 4 + 0][lr] = av.x;
        As[lc4 * 4 + 1][lr] = av.y;
        As[lc4 * 4 + 2][lr] = av.z;
        As[lc4 * 4 + 3][lr] = av.w;
        float4 bv = B4[(long)(k0 + br) * N4 + (colBase >> 2) + bc4];
        *(float4*)&Bs[br][bc4 * 4] = bv;
        __syncthreads();
#pragma unroll
        for (int k = 0; k < BK; ++k) {
            float4 a4v = *(const float4*)&As[k][ty * 4];
            float4 b4v = *(const float4*)&Bs[k][tx * 4];
            float aa[4] = {a4v.x, a4v.y, a4v.z, a4v.w};
            float bb[4] = {b4v.x, b4v.y, b4v.z, b4v.w};
#pragma unroll
            for (int i = 0; i < 4; ++i)
#pragma unroll
                for (int j = 0; j < 4; ++j)
                    acc[i][j] = fmaf(aa[i], bb[j], acc[i][j]);
        }
        __syncthreads();
    }
#pragma unroll
    for (int i = 0; i < 4; ++i) {
        int row = rowBase + ty * 4 + i;
        if (row < M) {
            ushort4 o;
            o.x = f2bf(acc[i][0]); o.y = f2bf(acc[i][1]);
            o.z = f2bf(acc[i][2]); o.w = f2bf(acc[i][3]);
            *(ushort4*)&Cb[(long)row * Ncol + colBase + tx * 4] = o;
        }
    }
}

// ====== MFMA GEMM: C = A(bf16) @ Bt(bf16), BM=128 BN=64 BK=32 ==============
template<bool RELU, bool BIAS, bool OUTBF>
__global__ __launch_bounds__(256) void k_gemm_mfma(
        const unsigned short* __restrict__ A, const unsigned short* __restrict__ Bt,
        const float* __restrict__ bias, float* __restrict__ Cf,
        unsigned short* __restrict__ Cb, int M, int K, int Ncol) {
    __shared__ unsigned short Ash[128][40];
    __shared__ unsigned short Bsh[64][40];
    const int tid = threadIdx.x;
    const int lane = tid & 63, w = tid >> 6;
    const int fr = lane & 15, quad = lane >> 4;
    const int wm0 = w * 32;
    const int rowBase = blockIdx.x * 128;
    const int colBase = blockIdx.y * 64;

    const int arow = tid >> 1;
    const int ahalf = (tid & 1) << 4;
    int agrow = rowBase + arow; if (agrow >= M) agrow = M - 1;
    const long abase = (long)agrow * K + ahalf;
    const int brow = tid >> 2;
    const int bseg = (tid & 3) << 3;
    const long bbase = (long)(colBase + brow) * K + bseg;

    f32x4 acc[2][4];
#pragma unroll
    for (int i = 0; i < 2; ++i)
#pragma unroll
        for (int j = 0; j < 4; ++j) acc[i][j] = (f32x4){0.f, 0.f, 0.f, 0.f};

    for (int k0 = 0; k0 < K; k0 += 32) {
        *(bf16x8*)&Ash[arow][ahalf]     = *(const bf16x8*)&A[abase + k0];
        *(bf16x8*)&Ash[arow][ahalf + 8] = *(const bf16x8*)&A[abase + k0 + 8];
        *(bf16x8*)&Bsh[brow][bseg]      = *(const bf16x8*)&Bt[bbase + k0];
        __syncthreads();
        bf16x8 ahf[2], bhf[4];
#pragma unroll
        for (int i = 0; i < 2; ++i)
            ahf[i] = *(const bf16x8*)&Ash[wm0 + i * 16 + fr][quad * 8];
#pragma unroll
        for (int j = 0; j < 4; ++j)
            bhf[j] = *(const bf16x8*)&Bsh[j * 16 + fr][quad * 8];
#pragma unroll
        for (int i = 0; i < 2; ++i)
#pragma unroll
            for (int j = 0; j < 4; ++j)
                acc[i][j] = __builtin_amdgcn_mfma_f32_16x16x32_bf16(
                    ahf[i], bhf[j], acc[i][j], 0, 0, 0);
        __syncthreads();
    }

#pragma unroll
    for (int i = 0; i < 2; ++i) {
        const int rowb = rowBase + wm0 + i * 16 + quad * 4;
#pragma unroll
        for (int j = 0; j < 4; ++j) {
            const int col = colBase + j * 16 + fr;
            const float bv = BIAS ? bias[col] : 0.f;
#pragma unroll
            for (int r = 0; r < 4; ++r) {
                const int row = rowb + r;
                if (row < M) {
                    float v = acc[i][j][r] + bv;
                    if (RELU) v = fmaxf(v, 0.f);
                    const long o = (long)row * Ncol + col;
                    if (OUTBF) Cb[o] = f2bf(v);
                    else       Cf[o] = v;
                }
            }
        }
    }
}

// == fused heads: [mu|lv] = h2 @ Wml; z; cap — BM=64 BN=128 K=256 ===========
__global__ __launch_bounds__(256) void k_gemm_heads(
        const unsigned short* __restrict__ A, const unsigned short* __restrict__ Bt,
        const float* __restrict__ bmu, const float* __restrict__ blv,
        const float* __restrict__ eps, const float* __restrict__ Wcap,
        const float* __restrict__ bcap, float* __restrict__ mu,
        float* __restrict__ lv, unsigned short* __restrict__ Zh,
        float* __restrict__ cap, int M) {
    constexpr int K = 256;
    __shared__ unsigned short Ash[64][40];
    __shared__ unsigned short Bsh[128][40];
    const int tid = threadIdx.x;
    const int lane = tid & 63, w = tid >> 6;
    const int fr = lane & 15, quad = lane >> 4;
    const int wm0 = w * 16;
    const int rowBase = blockIdx.x * 64;

    const int arow = tid >> 2;
    const int aseg = (tid & 3) << 3;
    int agrow = rowBase + arow; if (agrow >= M) agrow = M - 1;
    const long abase = (long)agrow * K + aseg;
    const int brow = tid >> 1;
    const int bseg = (tid & 1) << 4;
    const long bbase = (long)brow * K + bseg;

    f32x4 acc[8];
#pragma unroll
    for (int j = 0; j < 8; ++j) acc[j] = (f32x4){0.f, 0.f, 0.f, 0.f};

    for (int k0 = 0; k0 < K; k0 += 32) {
        *(bf16x8*)&Ash[arow][aseg] = *(const bf16x8*)&A[abase + k0];
        *(bf16x8*)&Bsh[brow][bseg]     = *(const bf16x8*)&Bt[bbase + k0];
        *(bf16x8*)&Bsh[brow][bseg + 8] = *(const bf16x8*)&Bt[bbase + k0 + 8];
        __syncthreads();
        bf16x8 ahf = *(const bf16x8*)&Ash[wm0 + fr][quad * 8];
#pragma unroll
        for (int j = 0; j < 8; ++j) {
            bf16x8 bhf = *(const bf16x8*)&Bsh[j * 16 + fr][quad * 8];
            acc[j] = __builtin_amdgcn_mfma_f32_16x16x32_bf16(ahf, bhf, acc[j], 0, 0, 0);
        }
        __syncthreads();
    }

    float capacc[4] = {0.f, 0.f, 0.f, 0.f};
#pragma unroll
    for (int j = 0; j < 4; ++j) {
        const int c = j * 16 + fr;
        const float bm = bmu[c], bl = blv[c];
        const float wc = Wcap[c];
#pragma unroll
        for (int r = 0; r < 4; ++r) {
            const int row = rowBase + wm0 + quad * 4 + r;
            if (row < M) {
                const long o = (long)row * 64 + c;
                float mv = acc[j][r] + bm;
                float lvv = acc[j + 4][r] + bl;
                mu[o] = mv;
                lv[o] = lvv;
                float zz = fmaf(eps[o], expf(0.5f * lvv), mv);
                Zh[o] = f2bf(zz);
                capacc[r] = fmaf(zz, wc, capacc[r]);
            }
        }
    }
    const float b0 = bcap[0];
#pragma unroll
    for (int r = 0; r < 4; ++r) {
        float v = capacc[r];
        v += __shfl_xor(v, 1, 64);
        v += __shfl_xor(v, 2, 64);
        v += __shfl_xor(v, 4, 64);
        v += __shfl_xor(v, 8, 64);
        if (fr == 0) {
            const int row = rowBase + wm0 + quad * 4 + r;
            if (row < M) cap[row] = 1.f / (1.f + expf(-(v + b0)));
        }
    }
}

// ==== conv1 agg: h1 = relu(b1 + sum_e w_e * T[tok_e]) ======================
__global__ __launch_bounds__(256) void k_agg_tab(
        const unsigned short* __restrict__ tab, const int* __restrict__ row_ptr,
        const int4* __restrict__ pack, const float* __restrict__ bias,
        unsigned short* __restrict__ h1, int N) {
    const int wave = threadIdx.x >> 6;
    const int lane = threadIdx.x & 63;
    const int node = blockIdx.x * 4 + wave;
    if (node >= N) return;
    const ushort4* t4 = (const ushort4*)tab;
    float ax = 0.f, ay = 0.f, az = 0.f, aw = 0.f;
    const int beg = row_ptr[node], end = row_ptr[node + 1];
    int e = beg;
    for (; e + 4 <= end; e += 4) {
        int4 p0 = pack[e], p1 = pack[e + 1], p2 = pack[e + 2], p3 = pack[e + 3];
        ushort4 v0 = t4[(long)p0.y * 64 + lane];
        ushort4 v1 = t4[(long)p1.y * 64 + lane];
        ushort4 v2 = t4[(long)p2.y * 64 + lane];
        ushort4 v3 = t4[(long)p3.y * 64 + lane];
        float w0 = __int_as_float(p0.x), w1 = __int_as_float(p1.x);
        float w2 = __int_as_float(p2.x), w3 = __int_as_float(p3.x);
        ax = fmaf(bf2f(v0.x), w0, ax); ay = fmaf(bf2f(v0.y), w0, ay);
        az = fmaf(bf2f(v0.z), w0, az); aw = fmaf(bf2f(v0.w), w0, aw);
        ax = fmaf(bf2f(v1.x), w1, ax); ay = fmaf(bf2f(v1.y), w1, ay);
        az = fmaf(bf2f(v1.z), w1, az); aw = fmaf(bf2f(v1.w), w1, aw);
        ax = fmaf(bf2f(v2.x), w2, ax); ay = fmaf(bf2f(v2.y), w2, ay);
        az = fmaf(bf2f(v2.z), w2, az); aw = fmaf(bf2f(v2.w), w2, aw);
        ax = fmaf(bf2f(v3.x), w3, ax); ay = fmaf(bf2f(v3.y), w3, ay);
        az = fmaf(bf2f(v3.z), w3, az); aw = fmaf(bf2f(v3.w), w3, aw);
    }
    for (; e < end; ++e) {
        int4 p = pack[e];
        float w0 = __int_as_float(p.x);
        ushort4 v = t4[(long)p.y * 64 + lane];
        ax = fmaf(bf2f(v.x), w0, ax); ay = fmaf(bf2f(v.y), w0, ay);
        az = fmaf(bf2f(v.z), w0, az); aw = fmaf(bf2f(v.w), w0, aw);
    }
    float4 b = ((const float4*)bias)[lane];
    ax = fmaxf(ax + b.x, 0.f); ay = fmaxf(ay + b.y, 0.f);
    az = fmaxf(az + b.z, 0.f); aw = fmaxf(aw + b.w, 0.f);
    ushort4 o;
    o.x = f2bf(ax); o.y = f2bf(ay); o.z = f2bf(az); o.w = f2bf(aw);
    ((ushort4*)h1)[(long)node * 64 + lane] = o;
}

// ==== conv2 agg: a2 = sum_e w_e * h1[src_e] ================================
__global__ __launch_bounds__(256) void k_agg_nb(
        const unsigned short* __restrict__ h1, const int* __restrict__ row_ptr,
        const int4* __restrict__ pack, unsigned short* __restrict__ Ob, int N) {
    const int wave = threadIdx.x >> 6;
    const int lane = threadIdx.x & 63;
    const int node = blockIdx.x * 4 + wave;
    if (node >= N) return;
    const ushort4* h4 = (const ushort4*)h1;
    float ax = 0.f, ay = 0.f, az = 0.f, aw = 0.f;
    const int beg = row_ptr[node], end = row_ptr[node + 1];
    int e = beg;
    for (; e + 4 <= end; e += 4) {
        int4 p0 = pack[e], p1 = pack[e + 1], p2 = pack[e + 2], p3 = pack[e + 3];
        ushort4 v0 = h4[(long)p0.z * 64 + lane];
        ushort4 v1 = h4[(long)p1.z * 64 + lane];
        ushort4 v2 = h4[(long)p2.z * 64 + lane];
        ushort4 v3 = h4[(long)p3.z * 64 + lane];
        float w0 = __int_as_float(p0.x), w1 = __int_as_float(p1.x);
        float w2 = __int_as_float(p2.x), w3 = __int_as_float(p3.x);
        ax = fmaf(bf2f(v0.x), w0, ax); ay = fmaf(bf2f(v0.y), w0, ay);
        az = fmaf(bf2f(v0.z), w0, az); aw = fmaf(bf2f(v0.w), w0, aw);
        ax = fmaf(bf2f(v1.x), w1, ax); ay = fmaf(bf2f(v1.y), w1, ay);
        az = fmaf(bf2f(v1.z), w1, az); aw = fmaf(bf2f(v1.w), w1, aw);
        ax = fmaf(bf2f(v2.x), w2, ax); ay = fmaf(bf2f(v2.y), w2, ay);
        az = fmaf(bf2f(v2.z), w2, az); aw = fmaf(bf2f(v2.w), w2, aw);
        ax = fmaf(bf2f(v3.x), w3, ax); ay = fmaf(bf2f(v3.y), w3, ay);
        az = fmaf(bf2f(v3.z), w3, az); aw = fmaf(bf2f(v3.w), w3, aw);
    }
    for (; e < end; ++e) {
        int4 p = pack[e];
        float w0 = __int_as_float(p.x);
        ushort4 v = h4[(long)p.z * 64 + lane];
        ax = fmaf(bf2f(v.x), w0, ax); ay = fmaf(bf2f(v.y), w0, ay);
        az = fmaf(bf2f(v.z), w0, az); aw = fmaf(bf2f(v.w), w0, aw);
    }
    ushort4 o;
    o.x = f2bf(ax); o.y = f2bf(ay); o.z = f2bf(az); o.w = f2bf(aw);
    ((ushort4*)Ob)[(long)node * 64 + lane] = o;
}

extern "C" void kernel_launch(void* const* d_in, const int* in_sizes, int n_in,
                              void* d_out, int out_size, void* d_ws, size_t ws_size,
                              hipStream_t stream) {
    const int*   x    = (const int*)d_in[0];
    const int*   ei   = (const int*)d_in[1];
    const float* eps  = (const float*)d_in[2];
    const float* emb  = (const float*)d_in[3];
    const float* W1   = (const float*)d_in[4];
    const float* b1   = (const float*)d_in[5];
    const float* W2   = (const float*)d_in[6];
    const float* b2   = (const float*)d_in[7];
    const float* Wmu  = (const float*)d_in[8];
    const float* bmu  = (const float*)d_in[9];
    const float* Wlv  = (const float*)d_in[10];
    const float* blv  = (const float*)d_in[11];
    const float* W3   = (const float*)d_in[12];
    const float* b3   = (const float*)d_in[13];
    const float* W4   = (const float*)d_in[14];
    const float* b4   = (const float*)d_in[15];
    const float* Wcap = (const float*)d_in[16];
    const float* bcap = (const float*)d_in[17];

    const int N = in_sizes[0];
    const int E = in_sizes[1] / 2;
    const int H = in_sizes[5];            // 256
    const int L = in_sizes[9];            // 64
    const int V = in_sizes[15];           // 128
    const int F = in_sizes[4] / H;        // 128
    const int T = E + N;

    const int* src = ei;
    const int* dst = ei + E;

    // ---- workspace carve-up (degint+cursor adjacent: single memset) ----
    char* w = (char*)d_ws;
    unsigned short* h1b  = (unsigned short*)w; w += (size_t)N * H * 2;
    unsigned short* a2b  = (unsigned short*)w; w += (size_t)N * H * 2;
    unsigned short* h2b  = (unsigned short*)w; w += (size_t)N * H * 2;
    unsigned short* zh   = (unsigned short*)w; w += (size_t)N * L * 2;
    int*   degint = (int*)w;   w += (size_t)N * 4;
    int*   cursor = (int*)w;   w += (size_t)N * 4;
    int*   rowp   = (int*)w;   w += (size_t)(N + 1) * 4;
    float* dinv   = (float*)w; w += (size_t)N * 4;
    int*   bsum   = (int*)w;   w += 256 * 4;
    int4*  pack   = (int4*)w;  w += (size_t)T * 16;
    unsigned short* tabH = (unsigned short*)w; w += (size_t)V * H * 2;
    unsigned short* W2t  = (unsigned short*)w; w += (size_t)H * H * 2;
    unsigned short* Wml  = (unsigned short*)w; w += (size_t)H * 2 * L * 2;
    unsigned short* W3t  = (unsigned short*)w; w += (size_t)L * H * 2;
    unsigned short* W4t  = (unsigned short*)w; w += (size_t)H * V * 2;

    unsigned short* tb = a2b;   // a2 dead after GEMM2; reuse for t

    float* outp    = (float*)d_out;
    float* recon   = outp;                               // [N, V]
    float* cap     = outp + (size_t)N * V;               // [N, 1]
    float* mu      = outp + (size_t)N * V + N;           // [N, L]
    float* logvar  = mu + (size_t)N * L;                 // [N, L]

    const int nN  = (N + 255) / 256;
    const int nE  = (E + 255) / 256;
    const int nT4 = (T + 1023) / 1024;
    const int nSc = (N + SCAN_BLOCK - 1) / SCAN_BLOCK;
    const int gM128 = (N + 127) / 128;
    const int gM64  = (N + 63) / 64;

    // ---- degree / dinv / CSR pack ----
    hipMemsetAsync(degint, 0, (size_t)N * 8, stream);    // degint + cursor
    k_deg_count<<<nE, 256, 0, stream>>>(dst, degint, E);
    k_scan_local<<<nSc, SCAN_BLOCK, 0, stream>>>(degint, rowp, bsum, dinv, N);
    k_scan_bsum<<<1, 64, 0, stream>>>(bsum, nSc);
    k_scan_add<<<nN, 256, 0, stream>>>(rowp, bsum, N, T);
    k_fill<<<nT4, 256, 0, stream>>>(src, dst, x, dinv, rowp, cursor, pack, E, N);

    // ---- weight conversions: one launch, 5 jobs ----
    k_cvt_all<<<dim3((H * H + 255) / 256, 5), 256, 0, stream>>>(
        W2, W2t, H, H,
        Wmu, Wml, H, L,
        Wlv, Wml + (size_t)L * H, H, L,
        W3, W3t, L, H,
        W4, W4t, H, V);

    // ---- conv1: embW1 = emb @ W1 -> bf16 table; agg -> h1 bf16 ----
    k_gemm_f32<<<dim3(V / 64, H / 64), 256, 0, stream>>>(emb, W1, tabH, V, F, H);
    k_agg_tab<<<(N + 3) / 4, 256, 0, stream>>>(tabH, rowp, pack, b1, h1b, N);

    // ---- conv2: a2 = A_hat h1; h2 = relu(a2 @ W2 + b2) -> bf16 ----
    k_agg_nb<<<(N + 3) / 4, 256, 0, stream>>>(h1b, rowp, pack, a2b, N);
    k_gemm_mfma<true, true, true><<<dim3(gM128, H / 64), 256, 0, stream>>>(
        a2b, W2t, b2, nullptr, h2b, N, H, H);

    // ---- fused heads: mu, logvar, z, cap ----
    k_gemm_heads<<<gM64, 256, 0, stream>>>(
        h2b, Wml, bmu, blv, eps, Wcap, bcap, mu, logvar, zh, cap, N);

    // ---- decode: t = relu(z@W3+b3) bf16; recon = t@W4+b4 fp32 ----
    k_gemm_mfma<true, true, true><<<dim3(gM128, H / 64), 256, 0, stream>>>(
        zh, W3t, b3, nullptr, tb, N, L, H);
    k_gemm_mfma<false, true, false><<<dim3(gM128, V / 64), 256, 0, stream>>>(
        tb, W4t, b4, recon, nullptr, N, H, V);
}

// Round 11
// 416.798 us; speedup vs baseline: 1.2378x; 1.0136x over previous
//
#include <hip/hip_runtime.h>
#include <math.h>

// ---------------------------------------------------------------------------
// GCN-VAE forward, round 11.
//  - conv1 GEMM-ified: agg over a 128-row table == c @ T where c[i][v] is the
//    summed edge weight per token. k_coef builds c in registers (broadcast
//    pack load + compare-add; NO gathers), then the proven MFMA GEMM does
//    h1 = relu(c @ T + b1). Replaces the 61us latency-bound k_agg_tab
//    (R10: 34MB @ 7% HBM, VALU 31% -- pure gather-issue cost).
//  - k_gemm_f32 writes the table transposed [H][V] bf16 for the B layout.
// ---------------------------------------------------------------------------

typedef __attribute__((ext_vector_type(8))) short bf16x8;
typedef __attribute__((ext_vector_type(4))) float f32x4;

__device__ inline unsigned short f2bf(float x) {
    unsigned u = __float_as_uint(x);
    return (unsigned short)((u + 0x7FFFu + ((u >> 16) & 1u)) >> 16);
}
__device__ inline float bf2f(unsigned short h) {
    return __uint_as_float(((unsigned)h) << 16);
}

// ============================ CSR build ====================================
__global__ __launch_bounds__(256) void k_deg_count(const int* __restrict__ dst,
                                                   int* __restrict__ degint, int E) {
    int e = blockIdx.x * 256 + threadIdx.x;
    if (e < E) atomicAdd(&degint[dst[e]], 1);
}

#define SCAN_BLOCK 1024
__global__ __launch_bounds__(SCAN_BLOCK) void k_scan_local(
        const int* __restrict__ degint, int* __restrict__ row_ptr,
        int* __restrict__ bsum, float* __restrict__ dinv, int N) {
    __shared__ int s[SCAN_BLOCK];
    int gid = blockIdx.x * SCAN_BLOCK + threadIdx.x;
    int d = (gid < N) ? (degint[gid] + 1) : 0;     // +1 self-loop
    if (gid < N) dinv[gid] = rsqrtf((float)d);
    s[threadIdx.x] = d;
    __syncthreads();
    for (int off = 1; off < SCAN_BLOCK; off <<= 1) {
        int t = (threadIdx.x >= off) ? s[threadIdx.x - off] : 0;
        __syncthreads();
        s[threadIdx.x] += t;
        __syncthreads();
    }
    if (gid < N) row_ptr[gid] = s[threadIdx.x] - d;          // exclusive
    if (threadIdx.x == SCAN_BLOCK - 1) bsum[blockIdx.x] = s[SCAN_BLOCK - 1];
}

__global__ void k_scan_bsum(int* __restrict__ bsum, int nb) {
    if (blockIdx.x == 0 && threadIdx.x == 0) {
        int acc = 0;
        for (int i = 0; i < nb; ++i) { int v = bsum[i]; bsum[i] = acc; acc += v; }
    }
}

__global__ __launch_bounds__(256) void k_scan_add(int* __restrict__ row_ptr,
                                                  const int* __restrict__ bsum,
                                                  int N, int T) {
    int gid = blockIdx.x * 256 + threadIdx.x;
    if (gid < N) row_ptr[gid] += bsum[gid / SCAN_BLOCK];
    if (gid == 0) row_ptr[N] = T;                 // T = E + N
}

// fill packs: pack = {w, x[src], src, 0}; 4 edges per thread for MLP
__global__ __launch_bounds__(256) void k_fill(
        const int* __restrict__ src, const int* __restrict__ dst,
        const int* __restrict__ x, const float* __restrict__ dinv,
        const int* __restrict__ row_ptr, int* __restrict__ cursor,
        int4* __restrict__ pack, int E, int N) {
    const int base = (blockIdx.x * 256 + threadIdx.x) * 4;
#pragma unroll
    for (int j = 0; j < 4; ++j) {
        int e = base + j;
        if (e < E) {
            int s = src[e], d = dst[e];
            float w = dinv[s] * dinv[d];
            int pos = row_ptr[d] + atomicAdd(&cursor[d], 1);
            pack[pos] = make_int4(__float_as_int(w), x[s], s, 0);
        } else if (e < E + N) {
            int i = e - E;
            float di = dinv[i];
            int pos = row_ptr[i] + atomicAdd(&cursor[i], 1);
            pack[pos] = make_int4(__float_as_int(di * di), x[i], i, 0);
        }
    }
}

// ===== merged weight transpose: 5 jobs, B[K,N] -> Bt[N,K] bf16 =============
__global__ __launch_bounds__(256) void k_cvt_all(
        const float* __restrict__ B0, unsigned short* __restrict__ h0, int K0, int N0,
        const float* __restrict__ B1, unsigned short* __restrict__ h1, int K1, int N1,
        const float* __restrict__ B2, unsigned short* __restrict__ h2, int K2, int N2,
        const float* __restrict__ B3, unsigned short* __restrict__ h3, int K3, int N3,
        const float* __restrict__ B4, unsigned short* __restrict__ h4, int K4, int N4) {
    const float* B; unsigned short* Bh; int K, Ncol;
    switch (blockIdx.y) {
        case 0: B = B0; Bh = h0; K = K0; Ncol = N0; break;
        case 1: B = B1; Bh = h1; K = K1; Ncol = N1; break;
        case 2: B = B2; Bh = h2; K = K2; Ncol = N2; break;
        case 3: B = B3; Bh = h3; K = K3; Ncol = N3; break;
        default: B = B4; Bh = h4; K = K4; Ncol = N4; break;
    }
    int i = blockIdx.x * 256 + threadIdx.x;
    if (i >= K * Ncol) return;
    int k = i / Ncol, n = i - k * Ncol;
    Bh[(long)n * K + k] = f2bf(B[i]);
}

// ==== small fp32 GEMM writing TRANSPOSED bf16 output: tabT[col][row] =======
__global__ __launch_bounds__(256) void k_gemm_f32t(
        const float* __restrict__ A, const float* __restrict__ B,
        unsigned short* __restrict__ CbT, int M, int K, int Ncol) {
    constexpr int BM = 64, BN = 64, BK = 16;
    __shared__ float As[BK][BM];
    __shared__ float Bs[BK][BN];
    const int tid = threadIdx.x;
    const int tx = tid & 15, ty = tid >> 4;
    const int rowBase = blockIdx.x * BM;
    const int colBase = blockIdx.y * BN;
    const int lr = tid >> 2, lc4 = tid & 3;
    const int br = tid >> 4, bc4 = tid & 15;
    const int arow = rowBase + lr;
    const int K4 = K >> 2, N4 = Ncol >> 2;
    const float4* A4 = (const float4*)A;
    const float4* B4 = (const float4*)B;
    float acc[4][4] = {{0.f}};
    for (int k0 = 0; k0 < K; k0 += BK) {
        float4 av = make_float4(0.f, 0.f, 0.f, 0.f);
        if (arow < M) av = A4[(long)arow * K4 + (k0 >> 2) + lc4];
        As[lc4 * 4 + 0][lr] = av.x;
        As[lc4 * 4 + 1][lr] = av.y;
        As[lc4 * 4 + 2][lr] = av.z;
        As[lc4 * 4 + 3][lr] = av.w;
        float4 bv = B4[(long)(k0 + br) * N4 + (colBase >> 2) + bc4];
        *(float4*)&Bs[br][bc4 * 4] = bv;
        __syncthreads();
#pragma unroll
        for (int k = 0; k < BK; ++k) {
            float4 a4v = *(const float4*)&As[k][ty * 4];
            float4 b4v = *(const float4*)&Bs[k][tx * 4];
            float aa[4] = {a4v.x, a4v.y, a4v.z, a4v.w};
            float bb[4] = {b4v.x, b4v.y, b4v.z, b4v.w};
#pragma unroll
            for (int i = 0; i < 4; ++i)
#pragma unroll
                for (int j = 0; j < 4; ++j)
                    acc[i][j] = fmaf(aa[i], bb[j], acc[i][j]);
        }
        __syncthreads();
    }
#pragma unroll
    for (int i = 0; i < 4; ++i) {
        int row = rowBase + ty * 4 + i;
        if (row < M) {
#pragma unroll
            for (int c = 0; c < 4; ++c) {
                int col = colBase + tx * 4 + c;
                CbT[(long)col * M + row] = f2bf(acc[i][c]);   // [Ncol][M]
            }
        }
    }
}

// ==== conv1 coefficients: c[i][v] = sum of w_e with tok_e == v =============
// Wave per node; lane owns tokens {lane, lane+64}. Broadcast 8B pack loads,
// compare-add; no gathers. Output bf16 [N][128].
__global__ __launch_bounds__(256) void k_coef(
        const int4* __restrict__ pack, const int* __restrict__ row_ptr,
        unsigned short* __restrict__ cb, int N) {
    const int wave = threadIdx.x >> 6;
    const int lane = threadIdx.x & 63;
    const int node = blockIdx.x * 4 + wave;
    if (node >= N) return;
    const int tok0 = lane, tok1 = lane + 64;
    float c0 = 0.f, c1 = 0.f;
    const int beg = row_ptr[node], end = row_ptr[node + 1];
    int e = beg;
    for (; e + 4 <= end; e += 4) {
        int2 p0 = *(const int2*)&pack[e];
        int2 p1 = *(const int2*)&pack[e + 1];
        int2 p2 = *(const int2*)&pack[e + 2];
        int2 p3 = *(const int2*)&pack[e + 3];
        c0 += (p0.y == tok0) ? __int_as_float(p0.x) : 0.f;
        c1 += (p0.y == tok1) ? __int_as_float(p0.x) : 0.f;
        c0 += (p1.y == tok0) ? __int_as_float(p1.x) : 0.f;
        c1 += (p1.y == tok1) ? __int_as_float(p1.x) : 0.f;
        c0 += (p2.y == tok0) ? __int_as_float(p2.x) : 0.f;
        c1 += (p2.y == tok1) ? __int_as_float(p2.x) : 0.f;
        c0 += (p3.y == tok0) ? __int_as_float(p3.x) : 0.f;
        c1 += (p3.y == tok1) ? __int_as_float(p3.x) : 0.f;
    }
    for (; e < end; ++e) {
        int2 p = *(const int2*)&pack[e];
        c0 += (p.y == tok0) ? __int_as_float(p.x) : 0.f;
        c1 += (p.y == tok1) ? __int_as_float(p.x) : 0.f;
    }
    const long base = (long)node * 128;
    cb[base + lane]      = f2bf(c0);
    cb[base + lane + 64] = f2bf(c1);
}

// ====== MFMA GEMM: C = A(bf16) @ Bt(bf16), BM=128 BN=64 BK=32 ==============
template<bool RELU, bool BIAS, bool OUTBF>
__global__ __launch_bounds__(256) void k_gemm_mfma(
        const unsigned short* __restrict__ A, const unsigned short* __restrict__ Bt,
        const float* __restrict__ bias, float* __restrict__ Cf,
        unsigned short* __restrict__ Cb, int M, int K, int Ncol) {
    __shared__ unsigned short Ash[128][40];
    __shared__ unsigned short Bsh[64][40];
    const int tid = threadIdx.x;
    const int lane = tid & 63, w = tid >> 6;
    const int fr = lane & 15, quad = lane >> 4;
    const int wm0 = w * 32;
    const int rowBase = blockIdx.x * 128;
    const int colBase = blockIdx.y * 64;

    const int arow = tid >> 1;
    const int ahalf = (tid & 1) << 4;
    int agrow = rowBase + arow; if (agrow >= M) agrow = M - 1;
    const long abase = (long)agrow * K + ahalf;
    const int brow = tid >> 2;
    const int bseg = (tid & 3) << 3;
    const long bbase = (long)(colBase + brow) * K + bseg;

    f32x4 acc[2][4];
#pragma unroll
    for (int i = 0; i < 2; ++i)
#pragma unroll
        for (int j = 0; j < 4; ++j) acc[i][j] = (f32x4){0.f, 0.f, 0.f, 0.f};

    for (int k0 = 0; k0 < K; k0 += 32) {
        *(bf16x8*)&Ash[arow][ahalf]     = *(const bf16x8*)&A[abase + k0];
        *(bf16x8*)&Ash[arow][ahalf + 8] = *(const bf16x8*)&A[abase + k0 + 8];
        *(bf16x8*)&Bsh[brow][bseg]      = *(const bf16x8*)&Bt[bbase + k0];
        __syncthreads();
        bf16x8 ahf[2], bhf[4];
#pragma unroll
        for (int i = 0; i < 2; ++i)
            ahf[i] = *(const bf16x8*)&Ash[wm0 + i * 16 + fr][quad * 8];
#pragma unroll
        for (int j = 0; j < 4; ++j)
            bhf[j] = *(const bf16x8*)&Bsh[j * 16 + fr][quad * 8];
#pragma unroll
        for (int i = 0; i < 2; ++i)
#pragma unroll
            for (int j = 0; j < 4; ++j)
                acc[i][j] = __builtin_amdgcn_mfma_f32_16x16x32_bf16(
                    ahf[i], bhf[j], acc[i][j], 0, 0, 0);
        __syncthreads();
    }

#pragma unroll
    for (int i = 0; i < 2; ++i) {
        const int rowb = rowBase + wm0 + i * 16 + quad * 4;
#pragma unroll
        for (int j = 0; j < 4; ++j) {
            const int col = colBase + j * 16 + fr;
            const float bv = BIAS ? bias[col] : 0.f;
#pragma unroll
            for (int r = 0; r < 4; ++r) {
                const int row = rowb + r;
                if (row < M) {
                    float v = acc[i][j][r] + bv;
                    if (RELU) v = fmaxf(v, 0.f);
                    const long o = (long)row * Ncol + col;
                    if (OUTBF) Cb[o] = f2bf(v);
                    else       Cf[o] = v;
                }
            }
        }
    }
}

// == fused heads: [mu|lv] = h2 @ Wml; z; cap — BM=64 BN=128 K=256 ===========
__global__ __launch_bounds__(256) void k_gemm_heads(
        const unsigned short* __restrict__ A, const unsigned short* __restrict__ Bt,
        const float* __restrict__ bmu, const float* __restrict__ blv,
        const float* __restrict__ eps, const float* __restrict__ Wcap,
        const float* __restrict__ bcap, float* __restrict__ mu,
        float* __restrict__ lv, unsigned short* __restrict__ Zh,
        float* __restrict__ cap, int M) {
    constexpr int K = 256;
    __shared__ unsigned short Ash[64][40];
    __shared__ unsigned short Bsh[128][40];
    const int tid = threadIdx.x;
    const int lane = tid & 63, w = tid >> 6;
    const int fr = lane & 15, quad = lane >> 4;
    const int wm0 = w * 16;
    const int rowBase = blockIdx.x * 64;

    const int arow = tid >> 2;
    const int aseg = (tid & 3) << 3;
    int agrow = rowBase + arow; if (agrow >= M) agrow = M - 1;
    const long abase = (long)agrow * K + aseg;
    const int brow = tid >> 1;
    const int bseg = (tid & 1) << 4;
    const long bbase = (long)brow * K + bseg;

    f32x4 acc[8];
#pragma unroll
    for (int j = 0; j < 8; ++j) acc[j] = (f32x4){0.f, 0.f, 0.f, 0.f};

    for (int k0 = 0; k0 < K; k0 += 32) {
        *(bf16x8*)&Ash[arow][aseg] = *(const bf16x8*)&A[abase + k0];
        *(bf16x8*)&Bsh[brow][bseg]     = *(const bf16x8*)&Bt[bbase + k0];
        *(bf16x8*)&Bsh[brow][bseg + 8] = *(const bf16x8*)&Bt[bbase + k0 + 8];
        __syncthreads();
        bf16x8 ahf = *(const bf16x8*)&Ash[wm0 + fr][quad * 8];
#pragma unroll
        for (int j = 0; j < 8; ++j) {
            bf16x8 bhf = *(const bf16x8*)&Bsh[j * 16 + fr][quad * 8];
            acc[j] = __builtin_amdgcn_mfma_f32_16x16x32_bf16(ahf, bhf, acc[j], 0, 0, 0);
        }
        __syncthreads();
    }

    float capacc[4] = {0.f, 0.f, 0.f, 0.f};
#pragma unroll
    for (int j = 0; j < 4; ++j) {
        const int c = j * 16 + fr;
        const float bm = bmu[c], bl = blv[c];
        const float wc = Wcap[c];
#pragma unroll
        for (int r = 0; r < 4; ++r) {
            const int row = rowBase + wm0 + quad * 4 + r;
            if (row < M) {
                const long o = (long)row * 64 + c;
                float mv = acc[j][r] + bm;
                float lvv = acc[j + 4][r] + bl;
                mu[o] = mv;
                lv[o] = lvv;
                float zz = fmaf(eps[o], expf(0.5f * lvv), mv);
                Zh[o] = f2bf(zz);
                capacc[r] = fmaf(zz, wc, capacc[r]);
            }
        }
    }
    const float b0 = bcap[0];
#pragma unroll
    for (int r = 0; r < 4; ++r) {
        float v = capacc[r];
        v += __shfl_xor(v, 1, 64);
        v += __shfl_xor(v, 2, 64);
        v += __shfl_xor(v, 4, 64);
        v += __shfl_xor(v, 8, 64);
        if (fr == 0) {
            const int row = rowBase + wm0 + quad * 4 + r;
            if (row < M) cap[row] = 1.f / (1.f + expf(-(v + b0)));
        }
    }
}

// ==== conv2 agg: a2 = sum_e w_e * h1[src_e] ================================
__global__ __launch_bounds__(256) void k_agg_nb(
        const unsigned short* __restrict__ h1, const int* __restrict__ row_ptr,
        const int4* __restrict__ pack, unsigned short* __restrict__ Ob, int N) {
    const int wave = threadIdx.x >> 6;
    const int lane = threadIdx.x & 63;
    const int node = blockIdx.x * 4 + wave;
    if (node >= N) return;
    const ushort4* h4 = (const ushort4*)h1;
    float ax = 0.f, ay = 0.f, az = 0.f, aw = 0.f;
    const int beg = row_ptr[node], end = row_ptr[node + 1];
    int e = beg;
    for (; e + 4 <= end; e += 4) {
        int4 p0 = pack[e], p1 = pack[e + 1], p2 = pack[e + 2], p3 = pack[e + 3];
        ushort4 v0 = h4[(long)p0.z * 64 + lane];
        ushort4 v1 = h4[(long)p1.z * 64 + lane];
        ushort4 v2 = h4[(long)p2.z * 64 + lane];
        ushort4 v3 = h4[(long)p3.z * 64 + lane];
        float w0 = __int_as_float(p0.x), w1 = __int_as_float(p1.x);
        float w2 = __int_as_float(p2.x), w3 = __int_as_float(p3.x);
        ax = fmaf(bf2f(v0.x), w0, ax); ay = fmaf(bf2f(v0.y), w0, ay);
        az = fmaf(bf2f(v0.z), w0, az); aw = fmaf(bf2f(v0.w), w0, aw);
        ax = fmaf(bf2f(v1.x), w1, ax); ay = fmaf(bf2f(v1.y), w1, ay);
        az = fmaf(bf2f(v1.z), w1, az); aw = fmaf(bf2f(v1.w), w1, aw);
        ax = fmaf(bf2f(v2.x), w2, ax); ay = fmaf(bf2f(v2.y), w2, ay);
        az = fmaf(bf2f(v2.z), w2, az); aw = fmaf(bf2f(v2.w), w2, aw);
        ax = fmaf(bf2f(v3.x), w3, ax); ay = fmaf(bf2f(v3.y), w3, ay);
        az = fmaf(bf2f(v3.z), w3, az); aw = fmaf(bf2f(v3.w), w3, aw);
    }
    for (; e < end; ++e) {
        int4 p = pack[e];
        float w0 = __int_as_float(p.x);
        ushort4 v = h4[(long)p.z * 64 + lane];
        ax = fmaf(bf2f(v.x), w0, ax); ay = fmaf(bf2f(v.y), w0, ay);
        az = fmaf(bf2f(v.z), w0, az); aw = fmaf(bf2f(v.w), w0, aw);
    }
    ushort4 o;
    o.x = f2bf(ax); o.y = f2bf(ay); o.z = f2bf(az); o.w = f2bf(aw);
    ((ushort4*)Ob)[(long)node * 64 + lane] = o;
}

extern "C" void kernel_launch(void* const* d_in, const int* in_sizes, int n_in,
                              void* d_out, int out_size, void* d_ws, size_t ws_size,
                              hipStream_t stream) {
    const int*   x    = (const int*)d_in[0];
    const int*   ei   = (const int*)d_in[1];
    const float* eps  = (const float*)d_in[2];
    const float* emb  = (const float*)d_in[3];
    const float* W1   = (const float*)d_in[4];
    const float* b1   = (const float*)d_in[5];
    const float* W2   = (const float*)d_in[6];
    const float* b2   = (const float*)d_in[7];
    const float* Wmu  = (const float*)d_in[8];
    const float* bmu  = (const float*)d_in[9];
    const float* Wlv  = (const float*)d_in[10];
    const float* blv  = (const float*)d_in[11];
    const float* W3   = (const float*)d_in[12];
    const float* b3   = (const float*)d_in[13];
    const float* W4   = (const float*)d_in[14];
    const float* b4   = (const float*)d_in[15];
    const float* Wcap = (const float*)d_in[16];
    const float* bcap = (const float*)d_in[17];

    const int N = in_sizes[0];
    const int E = in_sizes[1] / 2;
    const int H = in_sizes[5];            // 256
    const int L = in_sizes[9];            // 64
    const int V = in_sizes[15];           // 128
    const int F = in_sizes[4] / H;        // 128
    const int T = E + N;

    const int* src = ei;
    const int* dst = ei + E;

    // ---- workspace carve-up ----
    char* w = (char*)d_ws;
    unsigned short* h1b  = (unsigned short*)w; w += (size_t)N * H * 2;
    unsigned short* a2b  = (unsigned short*)w; w += (size_t)N * H * 2;
    unsigned short* h2b  = (unsigned short*)w; w += (size_t)N * H * 2;
    unsigned short* zh   = (unsigned short*)w; w += (size_t)N * L * 2;
    unsigned short* cb   = (unsigned short*)w; w += (size_t)N * V * 2;  // coef
    int*   degint = (int*)w;   w += (size_t)N * 4;
    int*   cursor = (int*)w;   w += (size_t)N * 4;
    int*   rowp   = (int*)w;   w += (size_t)(N + 1) * 4;
    float* dinv   = (float*)w; w += (size_t)N * 4;
    int*   bsum   = (int*)w;   w += 256 * 4;
    int4*  pack   = (int4*)w;  w += (size_t)T * 16;
    unsigned short* tabT = (unsigned short*)w; w += (size_t)H * V * 2;  // [256][128]
    unsigned short* W2t  = (unsigned short*)w; w += (size_t)H * H * 2;
    unsigned short* Wml  = (unsigned short*)w; w += (size_t)H * 2 * L * 2;
    unsigned short* W3t  = (unsigned short*)w; w += (size_t)L * H * 2;
    unsigned short* W4t  = (unsigned short*)w; w += (size_t)H * V * 2;

    unsigned short* tb = a2b;   // a2 dead after GEMM2; reuse for t

    float* outp    = (float*)d_out;
    float* recon   = outp;                               // [N, V]
    float* cap     = outp + (size_t)N * V;               // [N, 1]
    float* mu      = outp + (size_t)N * V + N;           // [N, L]
    float* logvar  = mu + (size_t)N * L;                 // [N, L]

    const int nN  = (N + 255) / 256;
    const int nE  = (E + 255) / 256;
    const int nT4 = (T + 1023) / 1024;
    const int nSc = (N + SCAN_BLOCK - 1) / SCAN_BLOCK;
    const int gM128 = (N + 127) / 128;
    const int gM64  = (N + 63) / 64;

    // ---- degree / dinv / CSR pack ----
    hipMemsetAsync(degint, 0, (size_t)N * 8, stream);    // degint + cursor
    k_deg_count<<<nE, 256, 0, stream>>>(dst, degint, E);
    k_scan_local<<<nSc, SCAN_BLOCK, 0, stream>>>(degint, rowp, bsum, dinv, N);
    k_scan_bsum<<<1, 64, 0, stream>>>(bsum, nSc);
    k_scan_add<<<nN, 256, 0, stream>>>(rowp, bsum, N, T);
    k_fill<<<nT4, 256, 0, stream>>>(src, dst, x, dinv, rowp, cursor, pack, E, N);

    // ---- weight conversions: one launch, 5 jobs ----
    k_cvt_all<<<dim3((H * H + 255) / 256, 5), 256, 0, stream>>>(
        W2, W2t, H, H,
        Wmu, Wml, H, L,
        Wlv, Wml + (size_t)L * H, H, L,
        W3, W3t, L, H,
        W4, W4t, H, V);

    // ---- conv1 (GEMM-ified): tabT = (emb@W1)^T bf16; c coef; GEMM ----
    k_gemm_f32t<<<dim3(V / 64, H / 64), 256, 0, stream>>>(emb, W1, tabT, V, F, H);
    k_coef<<<(N + 3) / 4, 256, 0, stream>>>(pack, rowp, cb, N);
    k_gemm_mfma<true, true, true><<<dim3(gM128, H / 64), 256, 0, stream>>>(
        cb, tabT, b1, nullptr, h1b, N, V, H);

    // ---- conv2: a2 = A_hat h1; h2 = relu(a2 @ W2 + b2) -> bf16 ----
    k_agg_nb<<<(N + 3) / 4, 256, 0, stream>>>(h1b, rowp, pack, a2b, N);
    k_gemm_mfma<true, true, true><<<dim3(gM128, H / 64), 256, 0, stream>>>(
        a2b, W2t, b2, nullptr, h2b, N, H, H);

    // ---- fused heads: mu, logvar, z, cap ----
    k_gemm_heads<<<gM64, 256, 0, stream>>>(
        h2b, Wml, bmu, blv, eps, Wcap, bcap, mu, logvar, zh, cap, N);

    // ---- decode: t = relu(z@W3+b3) bf16; recon = t@W4+b4 fp32 ----
    k_gemm_mfma<true, true, true><<<dim3(gM128, H / 64), 256, 0, stream>>>(
        zh, W3t, b3, nullptr, tb, N, L, H);
    k_gemm_mfma<false, true, false><<<dim3(gM128, V / 64), 256, 0, stream>>>(
        tb, W4t, b4, recon, nullptr, N, H, V);
}

// Round 12
// 410.637 us; speedup vs baseline: 1.2563x; 1.0150x over previous
//
#include <hip/hip_runtime.h>
#include <math.h>

// ---------------------------------------------------------------------------
// GCN-VAE forward, round 12.
//  - k_agg_nb: 8-deep edge unroll (R11: 27% VALU / 45% HBM -> MLP-limited).
//  - decode fused: one kernel does t=relu(z@W3+b3) -> LDS -> recon=t@W4+b4,
//    killing the 51MB t round-trip (t LDS layout = C-frag write / A-frag read,
//    both patterns already verified in the working GEMMs).
// ---------------------------------------------------------------------------

typedef __attribute__((ext_vector_type(8))) short bf16x8;
typedef __attribute__((ext_vector_type(4))) float f32x4;

__device__ inline unsigned short f2bf(float x) {
    unsigned u = __float_as_uint(x);
    return (unsigned short)((u + 0x7FFFu + ((u >> 16) & 1u)) >> 16);
}
__device__ inline float bf2f(unsigned short h) {
    return __uint_as_float(((unsigned)h) << 16);
}

// ============================ CSR build ====================================
__global__ __launch_bounds__(256) void k_deg_count(const int* __restrict__ dst,
                                                   int* __restrict__ degint, int E) {
    int e = blockIdx.x * 256 + threadIdx.x;
    if (e < E) atomicAdd(&degint[dst[e]], 1);
}

#define SCAN_BLOCK 1024
__global__ __launch_bounds__(SCAN_BLOCK) void k_scan_local(
        const int* __restrict__ degint, int* __restrict__ row_ptr,
        int* __restrict__ bsum, float* __restrict__ dinv, int N) {
    __shared__ int s[SCAN_BLOCK];
    int gid = blockIdx.x * SCAN_BLOCK + threadIdx.x;
    int d = (gid < N) ? (degint[gid] + 1) : 0;     // +1 self-loop
    if (gid < N) dinv[gid] = rsqrtf((float)d);
    s[threadIdx.x] = d;
    __syncthreads();
    for (int off = 1; off < SCAN_BLOCK; off <<= 1) {
        int t = (threadIdx.x >= off) ? s[threadIdx.x - off] : 0;
        __syncthreads();
        s[threadIdx.x] += t;
        __syncthreads();
    }
    if (gid < N) row_ptr[gid] = s[threadIdx.x] - d;          // exclusive
    if (threadIdx.x == SCAN_BLOCK - 1) bsum[blockIdx.x] = s[SCAN_BLOCK - 1];
}

__global__ void k_scan_bsum(int* __restrict__ bsum, int nb) {
    if (blockIdx.x == 0 && threadIdx.x == 0) {
        int acc = 0;
        for (int i = 0; i < nb; ++i) { int v = bsum[i]; bsum[i] = acc; acc += v; }
    }
}

__global__ __launch_bounds__(256) void k_scan_add(int* __restrict__ row_ptr,
                                                  const int* __restrict__ bsum,
                                                  int N, int T) {
    int gid = blockIdx.x * 256 + threadIdx.x;
    if (gid < N) row_ptr[gid] += bsum[gid / SCAN_BLOCK];
    if (gid == 0) row_ptr[N] = T;                 // T = E + N
}

// fill packs: pack = {w, x[src], src, 0}; 4 edges per thread for MLP
__global__ __launch_bounds__(256) void k_fill(
        const int* __restrict__ src, const int* __restrict__ dst,
        const int* __restrict__ x, const float* __restrict__ dinv,
        const int* __restrict__ row_ptr, int* __restrict__ cursor,
        int4* __restrict__ pack, int E, int N) {
    const int base = (blockIdx.x * 256 + threadIdx.x) * 4;
#pragma unroll
    for (int j = 0; j < 4; ++j) {
        int e = base + j;
        if (e < E) {
            int s = src[e], d = dst[e];
            float w = dinv[s] * dinv[d];
            int pos = row_ptr[d] + atomicAdd(&cursor[d], 1);
            pack[pos] = make_int4(__float_as_int(w), x[s], s, 0);
        } else if (e < E + N) {
            int i = e - E;
            float di = dinv[i];
            int pos = row_ptr[i] + atomicAdd(&cursor[i], 1);
            pack[pos] = make_int4(__float_as_int(di * di), x[i], i, 0);
        }
    }
}

// ===== merged weight transpose: 5 jobs, B[K,N] -> Bt[N,K] bf16 =============
__global__ __launch_bounds__(256) void k_cvt_all(
        const float* __restrict__ B0, unsigned short* __restrict__ h0, int K0, int N0,
        const float* __restrict__ B1, unsigned short* __restrict__ h1, int K1, int N1,
        const float* __restrict__ B2, unsigned short* __restrict__ h2, int K2, int N2,
        const float* __restrict__ B3, unsigned short* __restrict__ h3, int K3, int N3,
        const float* __restrict__ B4, unsigned short* __restrict__ h4, int K4, int N4) {
    const float* B; unsigned short* Bh; int K, Ncol;
    switch (blockIdx.y) {
        case 0: B = B0; Bh = h0; K = K0; Ncol = N0; break;
        case 1: B = B1; Bh = h1; K = K1; Ncol = N1; break;
        case 2: B = B2; Bh = h2; K = K2; Ncol = N2; break;
        case 3: B = B3; Bh = h3; K = K3; Ncol = N3; break;
        default: B = B4; Bh = h4; K = K4; Ncol = N4; break;
    }
    int i = blockIdx.x * 256 + threadIdx.x;
    if (i >= K * Ncol) return;
    int k = i / Ncol, n = i - k * Ncol;
    Bh[(long)n * K + k] = f2bf(B[i]);
}

// ==== small fp32 GEMM writing TRANSPOSED bf16 output: tabT[col][row] =======
__global__ __launch_bounds__(256) void k_gemm_f32t(
        const float* __restrict__ A, const float* __restrict__ B,
        unsigned short* __restrict__ CbT, int M, int K, int Ncol) {
    constexpr int BM = 64, BN = 64, BK = 16;
    __shared__ float As[BK][BM];
    __shared__ float Bs[BK][BN];
    const int tid = threadIdx.x;
    const int tx = tid & 15, ty = tid >> 4;
    const int rowBase = blockIdx.x * BM;
    const int colBase = blockIdx.y * BN;
    const int lr = tid >> 2, lc4 = tid & 3;
    const int br = tid >> 4, bc4 = tid & 15;
    const int arow = rowBase + lr;
    const int K4 = K >> 2, N4 = Ncol >> 2;
    const float4* A4 = (const float4*)A;
    const float4* B4 = (const float4*)B;
    float acc[4][4] = {{0.f}};
    for (int k0 = 0; k0 < K; k0 += BK) {
        float4 av = make_float4(0.f, 0.f, 0.f, 0.f);
        if (arow < M) av = A4[(long)arow * K4 + (k0 >> 2) + lc4];
        As[lc4 * 4 + 0][lr] = av.x;
        As[lc4 * 4 + 1][lr] = av.y;
        As[lc4 * 4 + 2][lr] = av.z;
        As[lc4 * 4 + 3][lr] = av.w;
        float4 bv = B4[(long)(k0 + br) * N4 + (colBase >> 2) + bc4];
        *(float4*)&Bs[br][bc4 * 4] = bv;
        __syncthreads();
#pragma unroll
        for (int k = 0; k < BK; ++k) {
            float4 a4v = *(const float4*)&As[k][ty * 4];
            float4 b4v = *(const float4*)&Bs[k][tx * 4];
            float aa[4] = {a4v.x, a4v.y, a4v.z, a4v.w};
            float bb[4] = {b4v.x, b4v.y, b4v.z, b4v.w};
#pragma unroll
            for (int i = 0; i < 4; ++i)
#pragma unroll
                for (int j = 0; j < 4; ++j)
                    acc[i][j] = fmaf(aa[i], bb[j], acc[i][j]);
        }
        __syncthreads();
    }
#pragma unroll
    for (int i = 0; i < 4; ++i) {
        int row = rowBase + ty * 4 + i;
        if (row < M) {
#pragma unroll
            for (int c = 0; c < 4; ++c) {
                int col = colBase + tx * 4 + c;
                CbT[(long)col * M + row] = f2bf(acc[i][c]);   // [Ncol][M]
            }
        }
    }
}

// ==== conv1 coefficients: c[i][v] = sum of w_e with tok_e == v =============
__global__ __launch_bounds__(256) void k_coef(
        const int4* __restrict__ pack, const int* __restrict__ row_ptr,
        unsigned short* __restrict__ cb, int N) {
    const int wave = threadIdx.x >> 6;
    const int lane = threadIdx.x & 63;
    const int node = blockIdx.x * 4 + wave;
    if (node >= N) return;
    const int tok0 = lane, tok1 = lane + 64;
    float c0 = 0.f, c1 = 0.f;
    const int beg = row_ptr[node], end = row_ptr[node + 1];
    int e = beg;
    for (; e + 4 <= end; e += 4) {
        int2 p0 = *(const int2*)&pack[e];
        int2 p1 = *(const int2*)&pack[e + 1];
        int2 p2 = *(const int2*)&pack[e + 2];
        int2 p3 = *(const int2*)&pack[e + 3];
        c0 += (p0.y == tok0) ? __int_as_float(p0.x) : 0.f;
        c1 += (p0.y == tok1) ? __int_as_float(p0.x) : 0.f;
        c0 += (p1.y == tok0) ? __int_as_float(p1.x) : 0.f;
        c1 += (p1.y == tok1) ? __int_as_float(p1.x) : 0.f;
        c0 += (p2.y == tok0) ? __int_as_float(p2.x) : 0.f;
        c1 += (p2.y == tok1) ? __int_as_float(p2.x) : 0.f;
        c0 += (p3.y == tok0) ? __int_as_float(p3.x) : 0.f;
        c1 += (p3.y == tok1) ? __int_as_float(p3.x) : 0.f;
    }
    for (; e < end; ++e) {
        int2 p = *(const int2*)&pack[e];
        c0 += (p.y == tok0) ? __int_as_float(p.x) : 0.f;
        c1 += (p.y == tok1) ? __int_as_float(p.x) : 0.f;
    }
    const long base = (long)node * 128;
    cb[base + lane]      = f2bf(c0);
    cb[base + lane + 64] = f2bf(c1);
}

// ====== MFMA GEMM: C = A(bf16) @ Bt(bf16), BM=128 BN=64 BK=32 ==============
template<bool RELU, bool BIAS, bool OUTBF>
__global__ __launch_bounds__(256) void k_gemm_mfma(
        const unsigned short* __restrict__ A, const unsigned short* __restrict__ Bt,
        const float* __restrict__ bias, float* __restrict__ Cf,
        unsigned short* __restrict__ Cb, int M, int K, int Ncol) {
    __shared__ unsigned short Ash[128][40];
    __shared__ unsigned short Bsh[64][40];
    const int tid = threadIdx.x;
    const int lane = tid & 63, w = tid >> 6;
    const int fr = lane & 15, quad = lane >> 4;
    const int wm0 = w * 32;
    const int rowBase = blockIdx.x * 128;
    const int colBase = blockIdx.y * 64;

    const int arow = tid >> 1;
    const int ahalf = (tid & 1) << 4;
    int agrow = rowBase + arow; if (agrow >= M) agrow = M - 1;
    const long abase = (long)agrow * K + ahalf;
    const int brow = tid >> 2;
    const int bseg = (tid & 3) << 3;
    const long bbase = (long)(colBase + brow) * K + bseg;

    f32x4 acc[2][4];
#pragma unroll
    for (int i = 0; i < 2; ++i)
#pragma unroll
        for (int j = 0; j < 4; ++j) acc[i][j] = (f32x4){0.f, 0.f, 0.f, 0.f};

    for (int k0 = 0; k0 < K; k0 += 32) {
        *(bf16x8*)&Ash[arow][ahalf]     = *(const bf16x8*)&A[abase + k0];
        *(bf16x8*)&Ash[arow][ahalf + 8] = *(const bf16x8*)&A[abase + k0 + 8];
        *(bf16x8*)&Bsh[brow][bseg]      = *(const bf16x8*)&Bt[bbase + k0];
        __syncthreads();
        bf16x8 ahf[2], bhf[4];
#pragma unroll
        for (int i = 0; i < 2; ++i)
            ahf[i] = *(const bf16x8*)&Ash[wm0 + i * 16 + fr][quad * 8];
#pragma unroll
        for (int j = 0; j < 4; ++j)
            bhf[j] = *(const bf16x8*)&Bsh[j * 16 + fr][quad * 8];
#pragma unroll
        for (int i = 0; i < 2; ++i)
#pragma unroll
            for (int j = 0; j < 4; ++j)
                acc[i][j] = __builtin_amdgcn_mfma_f32_16x16x32_bf16(
                    ahf[i], bhf[j], acc[i][j], 0, 0, 0);
        __syncthreads();
    }

#pragma unroll
    for (int i = 0; i < 2; ++i) {
        const int rowb = rowBase + wm0 + i * 16 + quad * 4;
#pragma unroll
        for (int j = 0; j < 4; ++j) {
            const int col = colBase + j * 16 + fr;
            const float bv = BIAS ? bias[col] : 0.f;
#pragma unroll
            for (int r = 0; r < 4; ++r) {
                const int row = rowb + r;
                if (row < M) {
                    float v = acc[i][j][r] + bv;
                    if (RELU) v = fmaxf(v, 0.f);
                    const long o = (long)row * Ncol + col;
                    if (OUTBF) Cb[o] = f2bf(v);
                    else       Cf[o] = v;
                }
            }
        }
    }
}

// == fused heads: [mu|lv] = h2 @ Wml; z; cap — BM=64 BN=128 K=256 ===========
__global__ __launch_bounds__(256) void k_gemm_heads(
        const unsigned short* __restrict__ A, const unsigned short* __restrict__ Bt,
        const float* __restrict__ bmu, const float* __restrict__ blv,
        const float* __restrict__ eps, const float* __restrict__ Wcap,
        const float* __restrict__ bcap, float* __restrict__ mu,
        float* __restrict__ lv, unsigned short* __restrict__ Zh,
        float* __restrict__ cap, int M) {
    constexpr int K = 256;
    __shared__ unsigned short Ash[64][40];
    __shared__ unsigned short Bsh[128][40];
    const int tid = threadIdx.x;
    const int lane = tid & 63, w = tid >> 6;
    const int fr = lane & 15, quad = lane >> 4;
    const int wm0 = w * 16;
    const int rowBase = blockIdx.x * 64;

    const int arow = tid >> 2;
    const int aseg = (tid & 3) << 3;
    int agrow = rowBase + arow; if (agrow >= M) agrow = M - 1;
    const long abase = (long)agrow * K + aseg;
    const int brow = tid >> 1;
    const int bseg = (tid & 1) << 4;
    const long bbase = (long)brow * K + bseg;

    f32x4 acc[8];
#pragma unroll
    for (int j = 0; j < 8; ++j) acc[j] = (f32x4){0.f, 0.f, 0.f, 0.f};

    for (int k0 = 0; k0 < K; k0 += 32) {
        *(bf16x8*)&Ash[arow][aseg] = *(const bf16x8*)&A[abase + k0];
        *(bf16x8*)&Bsh[brow][bseg]     = *(const bf16x8*)&Bt[bbase + k0];
        *(bf16x8*)&Bsh[brow][bseg + 8] = *(const bf16x8*)&Bt[bbase + k0 + 8];
        __syncthreads();
        bf16x8 ahf = *(const bf16x8*)&Ash[wm0 + fr][quad * 8];
#pragma unroll
        for (int j = 0; j < 8; ++j) {
            bf16x8 bhf = *(const bf16x8*)&Bsh[j * 16 + fr][quad * 8];
            acc[j] = __builtin_amdgcn_mfma_f32_16x16x32_bf16(ahf, bhf, acc[j], 0, 0, 0);
        }
        __syncthreads();
    }

    float capacc[4] = {0.f, 0.f, 0.f, 0.f};
#pragma unroll
    for (int j = 0; j < 4; ++j) {
        const int c = j * 16 + fr;
        const float bm = bmu[c], bl = blv[c];
        const float wc = Wcap[c];
#pragma unroll
        for (int r = 0; r < 4; ++r) {
            const int row = rowBase + wm0 + quad * 4 + r;
            if (row < M) {
                const long o = (long)row * 64 + c;
                float mv = acc[j][r] + bm;
                float lvv = acc[j + 4][r] + bl;
                mu[o] = mv;
                lv[o] = lvv;
                float zz = fmaf(eps[o], expf(0.5f * lvv), mv);
                Zh[o] = f2bf(zz);
                capacc[r] = fmaf(zz, wc, capacc[r]);
            }
        }
    }
    const float b0 = bcap[0];
#pragma unroll
    for (int r = 0; r < 4; ++r) {
        float v = capacc[r];
        v += __shfl_xor(v, 1, 64);
        v += __shfl_xor(v, 2, 64);
        v += __shfl_xor(v, 4, 64);
        v += __shfl_xor(v, 8, 64);
        if (fr == 0) {
            const int row = rowBase + wm0 + quad * 4 + r;
            if (row < M) cap[row] = 1.f / (1.f + expf(-(v + b0)));
        }
    }
}

// ==== fused decode: t = relu(z@W3+b3) -> LDS; recon = t@W4+b4 ==============
// BM=64 rows/block, 256 thr = 4 waves (wave w: rows w*16..w*16+16).
// GEMM1: K=64, BN=256 (acc1[16]); t -> Ts LDS; GEMM2: K=256, BN=128 (acc2[8]).
__global__ __launch_bounds__(256) void k_gemm_decode(
        const unsigned short* __restrict__ Zh, const unsigned short* __restrict__ W3t,
        const unsigned short* __restrict__ W4t, const float* __restrict__ b3,
        const float* __restrict__ b4, float* __restrict__ recon, int M) {
    __shared__ unsigned short Zs[64][40];     // 5 KB
    __shared__ unsigned short Bsh[256][40];   // 20 KB (reused for W4 tiles)
    __shared__ unsigned short Ts[64][264];    // 33.8 KB, stride 528B (16B-mult)
    const int tid = threadIdx.x;
    const int lane = tid & 63, w = tid >> 6;
    const int fr = lane & 15, quad = lane >> 4;
    const int wm0 = w * 16;
    const int rowBase = blockIdx.x * 64;

    // GEMM1 staging maps
    const int zrow = tid & 63;                 // 0..63
    const int zseg = (tid >> 6) << 3;          // 0,8,16,24
    int zgrow = rowBase + zrow; if (zgrow >= M) zgrow = M - 1;
    const long zbase = (long)zgrow * 64 + zseg;

    f32x4 acc1[16];
#pragma unroll
    for (int j = 0; j < 16; ++j) acc1[j] = (f32x4){0.f, 0.f, 0.f, 0.f};

#pragma unroll
    for (int k0 = 0; k0 < 64; k0 += 32) {
        *(bf16x8*)&Zs[zrow][zseg] = *(const bf16x8*)&Zh[zbase + k0 - zseg + zseg];
        // NB: zbase already includes zseg; offset by k0 only:
        // (rewritten below correctly)
        __syncthreads();
        __syncthreads();
        break;
    }
    // --- correct GEMM1 loop (the above was a misstep guard; redo cleanly) ---
#pragma unroll
    for (int j = 0; j < 16; ++j) acc1[j] = (f32x4){0.f, 0.f, 0.f, 0.f};
    for (int k0 = 0; k0 < 64; k0 += 32) {
        *(bf16x8*)&Zs[zrow][zseg] = *(const bf16x8*)&Zh[(long)zgrow * 64 + k0 + zseg];
        {   // W3t tile: 256 rows x 32 k; 1 thread/row, 4 bf16x8
            const long wb = (long)tid * 64 + k0;
            *(bf16x8*)&Bsh[tid][0]  = *(const bf16x8*)&W3t[wb];
            *(bf16x8*)&Bsh[tid][8]  = *(const bf16x8*)&W3t[wb + 8];
            *(bf16x8*)&Bsh[tid][16] = *(const bf16x8*)&W3t[wb + 16];
            *(bf16x8*)&Bsh[tid][24] = *(const bf16x8*)&W3t[wb + 24];
        }
        __syncthreads();
        bf16x8 af = *(const bf16x8*)&Zs[wm0 + fr][quad * 8];
#pragma unroll
        for (int j = 0; j < 16; ++j) {
            bf16x8 bf = *(const bf16x8*)&Bsh[j * 16 + fr][quad * 8];
            acc1[j] = __builtin_amdgcn_mfma_f32_16x16x32_bf16(af, bf, acc1[j], 0, 0, 0);
        }
        __syncthreads();
    }

    // epilogue1 -> Ts (bf16), C layout: col=j*16+fr, row=wm0+quad*4+r
#pragma unroll
    for (int j = 0; j < 16; ++j) {
        const int col = j * 16 + fr;
        const float bv = b3[col];
#pragma unroll
        for (int r = 0; r < 4; ++r) {
            const int rl = wm0 + quad * 4 + r;
            Ts[rl][col] = f2bf(fmaxf(acc1[j][r] + bv, 0.f));
        }
    }
    __syncthreads();

    // GEMM2: recon = Ts @ W4t + b4; K=256, 128 cols
    f32x4 acc2[8];
#pragma unroll
    for (int j = 0; j < 8; ++j) acc2[j] = (f32x4){0.f, 0.f, 0.f, 0.f};
    const int br2 = tid >> 1;                  // 0..127
    const int bs2 = (tid & 1) << 4;            // 0|16
    for (int k0 = 0; k0 < 256; k0 += 32) {
        const long wb = (long)br2 * 256 + k0 + bs2;
        *(bf16x8*)&Bsh[br2][bs2]     = *(const bf16x8*)&W4t[wb];
        *(bf16x8*)&Bsh[br2][bs2 + 8] = *(const bf16x8*)&W4t[wb + 8];
        __syncthreads();
        bf16x8 at = *(const bf16x8*)&Ts[wm0 + fr][k0 + quad * 8];
#pragma unroll
        for (int j = 0; j < 8; ++j) {
            bf16x8 bf = *(const bf16x8*)&Bsh[j * 16 + fr][quad * 8];
            acc2[j] = __builtin_amdgcn_mfma_f32_16x16x32_bf16(at, bf, acc2[j], 0, 0, 0);
        }
        __syncthreads();
    }

#pragma unroll
    for (int j = 0; j < 8; ++j) {
        const int col = j * 16 + fr;
        const float bv = b4[col];
#pragma unroll
        for (int r = 0; r < 4; ++r) {
            const int row = rowBase + wm0 + quad * 4 + r;
            if (row < M) recon[(long)row * 128 + col] = acc2[j][r] + bv;
        }
    }
}

// ==== conv2 agg: a2 = sum_e w_e * h1[src_e]; 8-deep unroll =================
__global__ __launch_bounds__(256) void k_agg_nb(
        const unsigned short* __restrict__ h1, const int* __restrict__ row_ptr,
        const int4* __restrict__ pack, unsigned short* __restrict__ Ob, int N) {
    const int wave = threadIdx.x >> 6;
    const int lane = threadIdx.x & 63;
    const int node = blockIdx.x * 4 + wave;
    if (node >= N) return;
    const ushort4* h4 = (const ushort4*)h1;
    float ax = 0.f, ay = 0.f, az = 0.f, aw = 0.f;
    const int beg = row_ptr[node], end = row_ptr[node + 1];
    int e = beg;
    for (; e + 8 <= end; e += 8) {
        int4 p0 = pack[e],     p1 = pack[e + 1], p2 = pack[e + 2], p3 = pack[e + 3];
        int4 p4 = pack[e + 4], p5 = pack[e + 5], p6 = pack[e + 6], p7 = pack[e + 7];
        ushort4 v0 = h4[(long)p0.z * 64 + lane];
        ushort4 v1 = h4[(long)p1.z * 64 + lane];
        ushort4 v2 = h4[(long)p2.z * 64 + lane];
        ushort4 v3 = h4[(long)p3.z * 64 + lane];
        ushort4 v4 = h4[(long)p4.z * 64 + lane];
        ushort4 v5 = h4[(long)p5.z * 64 + lane];
        ushort4 v6 = h4[(long)p6.z * 64 + lane];
        ushort4 v7 = h4[(long)p7.z * 64 + lane];
        float w0 = __int_as_float(p0.x), w1 = __int_as_float(p1.x);
        float w2 = __int_as_float(p2.x), w3 = __int_as_float(p3.x);
        float w4 = __int_as_float(p4.x), w5 = __int_as_float(p5.x);
        float w6 = __int_as_float(p6.x), w7 = __int_as_float(p7.x);
        ax = fmaf(bf2f(v0.x), w0, ax); ay = fmaf(bf2f(v0.y), w0, ay);
        az = fmaf(bf2f(v0.z), w0, az); aw = fmaf(bf2f(v0.w), w0, aw);
        ax = fmaf(bf2f(v1.x), w1, ax); ay = fmaf(bf2f(v1.y), w1, ay);
        az = fmaf(bf2f(v1.z), w1, az); aw = fmaf(bf2f(v1.w), w1, aw);
        ax = fmaf(bf2f(v2.x), w2, ax); ay = fmaf(bf2f(v2.y), w2, ay);
        az = fmaf(bf2f(v2.z), w2, az); aw = fmaf(bf2f(v2.w), w2, aw);
        ax = fmaf(bf2f(v3.x), w3, ax); ay = fmaf(bf2f(v3.y), w3, ay);
        az = fmaf(bf2f(v3.z), w3, az); aw = fmaf(bf2f(v3.w), w3, aw);
        ax = fmaf(bf2f(v4.x), w4, ax); ay = fmaf(bf2f(v4.y), w4, ay);
        az = fmaf(bf2f(v4.z), w4, az); aw = fmaf(bf2f(v4.w), w4, aw);
        ax = fmaf(bf2f(v5.x), w5, ax); ay = fmaf(bf2f(v5.y), w5, ay);
        az = fmaf(bf2f(v5.z), w5, az); aw = fmaf(bf2f(v5.w), w5, aw);
        ax = fmaf(bf2f(v6.x), w6, ax); ay = fmaf(bf2f(v6.y), w6, ay);
        az = fmaf(bf2f(v6.z), w6, az); aw = fmaf(bf2f(v6.w), w6, aw);
        ax = fmaf(bf2f(v7.x), w7, ax); ay = fmaf(bf2f(v7.y), w7, ay);
        az = fmaf(bf2f(v7.z), w7, az); aw = fmaf(bf2f(v7.w), w7, aw);
    }
    for (; e + 4 <= end; e += 4) {
        int4 p0 = pack[e], p1 = pack[e + 1], p2 = pack[e + 2], p3 = pack[e + 3];
        ushort4 v0 = h4[(long)p0.z * 64 + lane];
        ushort4 v1 = h4[(long)p1.z * 64 + lane];
        ushort4 v2 = h4[(long)p2.z * 64 + lane];
        ushort4 v3 = h4[(long)p3.z * 64 + lane];
        float w0 = __int_as_float(p0.x), w1 = __int_as_float(p1.x);
        float w2 = __int_as_float(p2.x), w3 = __int_as_float(p3.x);
        ax = fmaf(bf2f(v0.x), w0, ax); ay = fmaf(bf2f(v0.y), w0, ay);
        az = fmaf(bf2f(v0.z), w0, az); aw = fmaf(bf2f(v0.w), w0, aw);
        ax = fmaf(bf2f(v1.x), w1, ax); ay = fmaf(bf2f(v1.y), w1, ay);
        az = fmaf(bf2f(v1.z), w1, az); aw = fmaf(bf2f(v1.w), w1, aw);
        ax = fmaf(bf2f(v2.x), w2, ax); ay = fmaf(bf2f(v2.y), w2, ay);
        az = fmaf(bf2f(v2.z), w2, az); aw = fmaf(bf2f(v2.w), w2, aw);
        ax = fmaf(bf2f(v3.x), w3, ax); ay = fmaf(bf2f(v3.y), w3, ay);
        az = fmaf(bf2f(v3.z), w3, az); aw = fmaf(bf2f(v3.w), w3, aw);
    }
    for (; e < end; ++e) {
        int4 p = pack[e];
        float w0 = __int_as_float(p.x);
        ushort4 v = h4[(long)p.z * 64 + lane];
        ax = fmaf(bf2f(v.x), w0, ax); ay = fmaf(bf2f(v.y), w0, ay);
        az = fmaf(bf2f(v.z), w0, az); aw = fmaf(bf2f(v.w), w0, aw);
    }
    ushort4 o;
    o.x = f2bf(ax); o.y = f2bf(ay); o.z = f2bf(az); o.w = f2bf(aw);
    ((ushort4*)Ob)[(long)node * 64 + lane] = o;
}

extern "C" void kernel_launch(void* const* d_in, const int* in_sizes, int n_in,
                              void* d_out, int out_size, void* d_ws, size_t ws_size,
                              hipStream_t stream) {
    const int*   x    = (const int*)d_in[0];
    const int*   ei   = (const int*)d_in[1];
    const float* eps  = (const float*)d_in[2];
    const float* emb  = (const float*)d_in[3];
    const float* W1   = (const float*)d_in[4];
    const float* b1   = (const float*)d_in[5];
    const float* W2   = (const float*)d_in[6];
    const float* b2   = (const float*)d_in[7];
    const float* Wmu  = (const float*)d_in[8];
    const float* bmu  = (const float*)d_in[9];
    const float* Wlv  = (const float*)d_in[10];
    const float* blv  = (const float*)d_in[11];
    const float* W3   = (const float*)d_in[12];
    const float* b3   = (const float*)d_in[13];
    const float* W4   = (const float*)d_in[14];
    const float* b4   = (const float*)d_in[15];
    const float* Wcap = (const float*)d_in[16];
    const float* bcap = (const float*)d_in[17];

    const int N = in_sizes[0];
    const int E = in_sizes[1] / 2;
    const int H = in_sizes[5];            // 256
    const int L = in_sizes[9];            // 64
    const int V = in_sizes[15];           // 128
    const int F = in_sizes[4] / H;        // 128
    const int T = E + N;

    const int* src = ei;
    const int* dst = ei + E;

    // ---- workspace carve-up ----
    char* w = (char*)d_ws;
    unsigned short* h1b  = (unsigned short*)w; w += (size_t)N * H * 2;
    unsigned short* a2b  = (unsigned short*)w; w += (size_t)N * H * 2;
    unsigned short* h2b  = (unsigned short*)w; w += (size_t)N * H * 2;
    unsigned short* zh   = (unsigned short*)w; w += (size_t)N * L * 2;
    unsigned short* cb   = (unsigned short*)w; w += (size_t)N * V * 2;  // coef
    int*   degint = (int*)w;   w += (size_t)N * 4;
    int*   cursor = (int*)w;   w += (size_t)N * 4;
    int*   rowp   = (int*)w;   w += (size_t)(N + 1) * 4;
    float* dinv   = (float*)w; w += (size_t)N * 4;
    int*   bsum   = (int*)w;   w += 256 * 4;
    int4*  pack   = (int4*)w;  w += (size_t)T * 16;
    unsigned short* tabT = (unsigned short*)w; w += (size_t)H * V * 2;  // [256][128]
    unsigned short* W2t  = (unsigned short*)w; w += (size_t)H * H * 2;
    unsigned short* Wml  = (unsigned short*)w; w += (size_t)H * 2 * L * 2;
    unsigned short* W3t  = (unsigned short*)w; w += (size_t)L * H * 2;  // [256][64]
    unsigned short* W4t  = (unsigned short*)w; w += (size_t)H * V * 2;  // [128][256]

    float* outp    = (float*)d_out;
    float* recon   = outp;                               // [N, V]
    float* cap     = outp + (size_t)N * V;               // [N, 1]
    float* mu      = outp + (size_t)N * V + N;           // [N, L]
    float* logvar  = mu + (size_t)N * L;                 // [N, L]

    const int nN  = (N + 255) / 256;
    const int nE  = (E + 255) / 256;
    const int nT4 = (T + 1023) / 1024;
    const int nSc = (N + SCAN_BLOCK - 1) / SCAN_BLOCK;
    const int gM128 = (N + 127) / 128;
    const int gM64  = (N + 63) / 64;

    // ---- degree / dinv / CSR pack ----
    hipMemsetAsync(degint, 0, (size_t)N * 8, stream);    // degint + cursor
    k_deg_count<<<nE, 256, 0, stream>>>(dst, degint, E);
    k_scan_local<<<nSc, SCAN_BLOCK, 0, stream>>>(degint, rowp, bsum, dinv, N);
    k_scan_bsum<<<1, 64, 0, stream>>>(bsum, nSc);
    k_scan_add<<<nN, 256, 0, stream>>>(rowp, bsum, N, T);
    k_fill<<<nT4, 256, 0, stream>>>(src, dst, x, dinv, rowp, cursor, pack, E, N);

    // ---- weight conversions: one launch, 5 jobs ----
    k_cvt_all<<<dim3((H * H + 255) / 256, 5), 256, 0, stream>>>(
        W2, W2t, H, H,
        Wmu, Wml, H, L,
        Wlv, Wml + (size_t)L * H, H, L,
        W3, W3t, L, H,
        W4, W4t, H, V);

    // ---- conv1 (GEMM-ified): tabT = (emb@W1)^T bf16; coef; GEMM ----
    k_gemm_f32t<<<dim3(V / 64, H / 64), 256, 0, stream>>>(emb, W1, tabT, V, F, H);
    k_coef<<<(N + 3) / 4, 256, 0, stream>>>(pack, rowp, cb, N);
    k_gemm_mfma<true, true, true><<<dim3(gM128, H / 64), 256, 0, stream>>>(
        cb, tabT, b1, nullptr, h1b, N, V, H);

    // ---- conv2: a2 = A_hat h1; h2 = relu(a2 @ W2 + b2) -> bf16 ----
    k_agg_nb<<<(N + 3) / 4, 256, 0, stream>>>(h1b, rowp, pack, a2b, N);
    k_gemm_mfma<true, true, true><<<dim3(gM128, H / 64), 256, 0, stream>>>(
        a2b, W2t, b2, nullptr, h2b, N, H, H);

    // ---- fused heads: mu, logvar, z, cap ----
    k_gemm_heads<<<gM64, 256, 0, stream>>>(
        h2b, Wml, bmu, blv, eps, Wcap, bcap, mu, logvar, zh, cap, N);

    // ---- fused decode: recon = relu(z@W3+b3)@W4 + b4 ----
    k_gemm_decode<<<gM64, 256, 0, stream>>>(zh, W3t, W4t, b3, b4, recon, N);
}